// Round 6
// baseline (370.657 us; speedup 1.0000x reference)
//
#include <hip/hip_runtime.h>
#include <hip/hip_fp16.h>
#include <cstddef>
#include <cstdint>

// N=50000, F_IN=128, HID=64, HEADS=4, E=800000, NG=64
// Layer1: x16[N,128]@W1p -> h1(fp16) via MFMA; GAT agg (precomputed edge weights) -> x2 fp16
// Layer2: x2@W2p -> h2(fp16) via MFMA; GAT agg -> out2 fp32
// Pool: segment-mean by sorted batch -> [64,64]; fc -> [64]

#define LOG2E 1.4426950408889634f
__device__ __forceinline__ float lrelu02(float x) { return x >= 0.f ? x : 0.2f * x; }
__device__ __forceinline__ float elu1(float x)    { return x > 0.f ? x : expm1f(x); }
__device__ __forceinline__ float fexp(float x)    { return exp2f(x * LOG2E); }

typedef _Float16 f16x8 __attribute__((ext_vector_type(8)));
typedef float    f32x4 __attribute__((ext_vector_type(4)));

// ---------------- CSR build (by destination) ----------------
__global__ void k_hist(const int* __restrict__ dst, int* __restrict__ cnt, int e) {
    int i = blockIdx.x * 256 + threadIdx.x;
    if (i < e) atomicAdd(&cnt[dst[i]], 1);
}

__global__ __launch_bounds__(1024) void k_scan(const int* __restrict__ cnt,
                                               int* __restrict__ rowptr,
                                               int* __restrict__ fill, int n) {
    __shared__ int wsums[16];
    const int t = threadIdx.x, lane = t & 63, wv = t >> 6;
    int carry = 0;
    if (t == 0) rowptr[0] = 0;
    for (int base = 0; base < n; base += 1024) {
        int i = base + t;
        int v = (i < n) ? cnt[i] : 0;
        int s = v;
#pragma unroll
        for (int d = 1; d < 64; d <<= 1) { int o = __shfl_up(s, d); if (lane >= d) s += o; }
        if (lane == 63) wsums[wv] = s;
        __syncthreads();
        if (t < 16) {
            int xx = wsums[t];
#pragma unroll
            for (int d = 1; d < 16; d <<= 1) { int o = __shfl_up(xx, d); if (t >= d) xx += o; }
            wsums[t] = xx;
        }
        __syncthreads();
        int add = carry + (wv > 0 ? wsums[wv - 1] : 0);
        int incl = s + add;
        if (i < n) { rowptr[i + 1] = incl; fill[i] = incl - v; }
        carry += wsums[15];
        __syncthreads();
    }
}

// also records each edge's CSR slot for the weight-precompute pass
__global__ void k_scatter(const int* __restrict__ src, const int* __restrict__ dstArr,
                          int* __restrict__ fill, int* __restrict__ csr,
                          int* __restrict__ epos, int e) {
    int i = blockIdx.x * 256 + threadIdx.x;
    if (i < e) {
        int d = dstArr[i];
        int p = atomicAdd(&fill[d], 1);
        csr[p] = src[i];
        epos[i] = p;
    }
}

// ---------------- fp32 -> fp16 convert (x) ----------------
__global__ void k_cvt16(const float* __restrict__ in, __half* __restrict__ outp, int n4) {
    int i = blockIdx.x * 256 + threadIdx.x;
    if (i >= n4) return;
    float4 v = *reinterpret_cast<const float4*>(in + (size_t)i * 4);
    __half2 h0 = __floats2half2_rn(v.x, v.y);
    __half2 h1 = __floats2half2_rn(v.z, v.w);
    int2 p;
    p.x = *reinterpret_cast<int*>(&h0);
    p.y = *reinterpret_cast<int*>(&h1);
    *reinterpret_cast<int2*>(outp + (size_t)i * 4) = p;
}

// ---------------- W pack: fp32 [K][N] row-major -> fragment-ordered fp16 ----------------
__global__ void k_packW(const float* __restrict__ W, __half* __restrict__ Bp, int K, int N) {
    int i = blockIdx.x * 256 + threadIdx.x;
    int total = (K / 32) * (N / 16) * 64;
    if (i >= total) return;
    int c = i & 15, q = (i >> 4) & 3, tnt = i >> 6;
    int nt = tnt % (N / 16), t = tnt / (N / 16);
    int k0 = t * 32 + q * 8, col = nt * 16 + c;
    __half tmp[8];
#pragma unroll
    for (int j = 0; j < 8; ++j) tmp[j] = __float2half(W[(size_t)(k0 + j) * N + col]);
    *reinterpret_cast<int4*>(Bp + (size_t)i * 8) = *reinterpret_cast<int4*>(tmp);
}

// ---------------- MFMA GEMM: C[M,N] = A[M,K] @ B[K,N], fp16 in, fp16 out ----------------
template <int K, int N>
__global__ __launch_bounds__(256) void k_gemm_mfma(const __half* __restrict__ A,
                                                   const __half* __restrict__ Bp,
                                                   __half* __restrict__ C, int M) {
    constexpr int NT = N / 16, KT = K / 32;
    const int lane = threadIdx.x & 63;
    const int wv = threadIdx.x >> 6;
    const int row0 = (blockIdx.x * 4 + wv) * 16;
    if (row0 >= M) return;

    f32x4 acc[NT];
#pragma unroll
    for (int nt = 0; nt < NT; ++nt) acc[nt] = (f32x4){0.f, 0.f, 0.f, 0.f};

    const __half* Ab = A + (size_t)(row0 + (lane & 15)) * K + (lane >> 4) * 8;
    const __half* Bb = Bp + (size_t)lane * 8;
#pragma unroll
    for (int t = 0; t < KT; ++t) {
        f16x8 a = *reinterpret_cast<const f16x8*>(Ab + t * 32);
#pragma unroll
        for (int nt = 0; nt < NT; ++nt) {
            f16x8 b = *reinterpret_cast<const f16x8*>(Bb + (size_t)(t * NT + nt) * 512);
            acc[nt] = __builtin_amdgcn_mfma_f32_16x16x32_f16(a, b, acc[nt], 0, 0, 0);
        }
    }
    const int r0 = row0 + (lane >> 4) * 4;
    const int cl = lane & 15;
#pragma unroll
    for (int nt = 0; nt < NT; ++nt) {
        int col = nt * 16 + cl;
#pragma unroll
        for (int j = 0; j < 4; ++j)
            C[(size_t)(r0 + j) * N + col] = __float2half(acc[nt][j]);
    }
}

__device__ __forceinline__ void load_h4(const __half* __restrict__ p, float2& lo, float2& hi) {
    float2 raw = *reinterpret_cast<const float2*>(p);   // 8B = 4 halves
    __half2* q = reinterpret_cast<__half2*>(&raw);
    lo = __half22float2(q[0]);
    hi = __half22float2(q[1]);
}

// ---------------- attention logits, layer 1 ----------------
__global__ void k_al1(const __half* __restrict__ h1, const float* __restrict__ a_src,
                      const float* __restrict__ a_dst, float* __restrict__ als,
                      float* __restrict__ ald, int n) {
    const int lane = threadIdx.x & 63;
    const int node = (blockIdx.x << 2) + (threadIdx.x >> 6);
    if (node >= n) return;
    const int head = lane >> 4;
    float2 lo, hi;
    load_h4(h1 + (size_t)node * 256 + lane * 4, lo, hi);
    float4 av = *reinterpret_cast<const float4*>(a_src + lane * 4);
    float4 dv = *reinterpret_cast<const float4*>(a_dst + lane * 4);
    float ps = lo.x * av.x + lo.y * av.y + hi.x * av.z + hi.y * av.w;
    float pd = lo.x * dv.x + lo.y * dv.y + hi.x * dv.z + hi.y * dv.w;
#pragma unroll
    for (int d = 1; d < 16; d <<= 1) { ps += __shfl_xor(ps, d); pd += __shfl_xor(pd, d); }
    if ((lane & 15) == 0) { als[node * 4 + head] = ps; ald[node * 4 + head] = pd; }
}

// ---------------- edge weight precompute, layer 1: w1[p*4+h] ----------------
__global__ void k_w1(const int* __restrict__ src, const int* __restrict__ dstArr,
                     const int* __restrict__ epos, const float* __restrict__ als,
                     const float* __restrict__ ald, float* __restrict__ w1, int e) {
    int i = blockIdx.x * 256 + threadIdx.x;
    if (i >= e) return;
    int s = src[i], d = dstArr[i], p = epos[i];
    float4 as = *reinterpret_cast<const float4*>(als + (size_t)s * 4);
    float4 ad = *reinterpret_cast<const float4*>(ald + (size_t)d * 4);
    float4 w;
    w.x = fexp(lrelu02(as.x + ad.x));
    w.y = fexp(lrelu02(as.y + ad.y));
    w.z = fexp(lrelu02(as.z + ad.z));
    w.w = fexp(lrelu02(as.w + ad.w));
    *reinterpret_cast<float4*>(w1 + (size_t)p * 4) = w;
}

// ---------------- edge weight precompute, layer 2: w2[p] ----------------
__global__ void k_w2(const int* __restrict__ src, const int* __restrict__ dstArr,
                     const int* __restrict__ epos, const float* __restrict__ als,
                     const float* __restrict__ ald, float* __restrict__ w2, int e) {
    int i = blockIdx.x * 256 + threadIdx.x;
    if (i >= e) return;
    w2[epos[i]] = fexp(lrelu02(als[src[i]] + ald[dstArr[i]]));
}

// ---------------- edge aggregation, layer 1 (precomputed weights) ----------------
__global__ void k_edge1(const __half* __restrict__ h1, const float* __restrict__ w1,
                        const float* __restrict__ als, const float* __restrict__ ald,
                        const int* __restrict__ rowptr, const int* __restrict__ csr,
                        const float* __restrict__ b1, __half* __restrict__ x2, int n) {
    const int lane = threadIdx.x & 63;
    const int node = (blockIdx.x << 2) + (threadIdx.x >> 6);
    if (node >= n) return;
    const int head = lane >> 4;
    const int ch = lane * 4;
    float ax = 0.f, ay = 0.f, az = 0.f, aw = 0.f, wsum = 0.f;
    const int beg = rowptr[node], end = rowptr[node + 1];
    int i = beg;
    for (; i + 2 <= end; i += 2) {
        int s0 = csr[i], s1 = csr[i + 1];
        float w0 = w1[(size_t)i * 4 + head];
        float w1v = w1[(size_t)(i + 1) * 4 + head];
        float2 l0, u0, l1, u1;
        load_h4(h1 + (size_t)s0 * 256 + ch, l0, u0);
        load_h4(h1 + (size_t)s1 * 256 + ch, l1, u1);
        ax += w0 * l0.x + w1v * l1.x;
        ay += w0 * l0.y + w1v * l1.y;
        az += w0 * u0.x + w1v * u1.x;
        aw += w0 * u0.y + w1v * u1.y;
        wsum += w0 + w1v;
    }
    if (i < end) {
        int s0 = csr[i];
        float w0 = w1[(size_t)i * 4 + head];
        float2 l0, u0;
        load_h4(h1 + (size_t)s0 * 256 + ch, l0, u0);
        ax += w0 * l0.x; ay += w0 * l0.y; az += w0 * u0.x; aw += w0 * u0.y;
        wsum += w0;
    }
    {   // self loop (weight computed inline: one exp per node)
        float a0 = als[node * 4 + head] + ald[node * 4 + head];
        float w0 = fexp(lrelu02(a0));
        float2 l0, u0;
        load_h4(h1 + (size_t)node * 256 + ch, l0, u0);
        ax += w0 * l0.x; ay += w0 * l0.y; az += w0 * u0.x; aw += w0 * u0.y;
        wsum += w0;
    }
    const float inv = 1.f / (wsum + 1e-16f);
    float4 bv = *reinterpret_cast<const float4*>(b1 + ch);
    __half2 r0 = __floats2half2_rn(elu1(ax * inv + bv.x), elu1(ay * inv + bv.y));
    __half2 r1 = __floats2half2_rn(elu1(az * inv + bv.z), elu1(aw * inv + bv.w));
    int2 p;
    p.x = *reinterpret_cast<int*>(&r0);
    p.y = *reinterpret_cast<int*>(&r1);
    *reinterpret_cast<int2*>(x2 + (size_t)node * 256 + ch) = p;
}

// ---------------- attention logits, layer 2 ----------------
__global__ void k_al2(const __half* __restrict__ h2, const float* __restrict__ a_src,
                      const float* __restrict__ a_dst, float* __restrict__ als,
                      float* __restrict__ ald, int n) {
    const int lane = threadIdx.x & 63;
    const int node = (blockIdx.x << 2) + (threadIdx.x >> 6);
    if (node >= n) return;
    float hv = __half2float(h2[(size_t)node * 64 + lane]);
    float ps = hv * a_src[lane];
    float pd = hv * a_dst[lane];
#pragma unroll
    for (int d = 1; d < 64; d <<= 1) { ps += __shfl_xor(ps, d); pd += __shfl_xor(pd, d); }
    if (lane == 0) { als[node] = ps; ald[node] = pd; }
}

// ---------------- edge aggregation, layer 2 (precomputed weights) ----------------
__global__ void k_edge2(const __half* __restrict__ h2, const float* __restrict__ w2,
                        const float* __restrict__ als, const float* __restrict__ ald,
                        const int* __restrict__ rowptr, const int* __restrict__ csr,
                        const float* __restrict__ b2, float* __restrict__ out2, int n) {
    const int lane = threadIdx.x & 63;
    const int node = (blockIdx.x << 2) + (threadIdx.x >> 6);
    if (node >= n) return;
    float acc = 0.f, wsum = 0.f;
    const int beg = rowptr[node], end = rowptr[node + 1];
    int i = beg;
    for (; i + 2 <= end; i += 2) {
        int s0 = csr[i], s1 = csr[i + 1];
        float w0 = w2[i], w1v = w2[i + 1];
        float v0 = __half2float(h2[(size_t)s0 * 64 + lane]);
        float v1 = __half2float(h2[(size_t)s1 * 64 + lane]);
        acc += w0 * v0 + w1v * v1;
        wsum += w0 + w1v;
    }
    if (i < end) {
        int s0 = csr[i];
        float w0 = w2[i];
        acc += w0 * __half2float(h2[(size_t)s0 * 64 + lane]);
        wsum += w0;
    }
    {   // self loop
        float w0 = fexp(lrelu02(als[node] + ald[node]));
        acc += w0 * __half2float(h2[(size_t)node * 64 + lane]);
        wsum += w0;
    }
    float o = acc / (wsum + 1e-16f) + b2[lane];
    out2[(size_t)node * 64 + lane] = elu1(o);
}

// ---------------- pool (mean by sorted batch) + fc ----------------
__global__ __launch_bounds__(1024) void k_pool(const float* __restrict__ out2,
                                               const int* __restrict__ batch,
                                               const float* __restrict__ fcW,
                                               const float* __restrict__ fcb,
                                               float* __restrict__ out, int n) {
    __shared__ float sbuf[16][64];
    const int g = blockIdx.x;
    const int lane = threadIdx.x & 63, wv = threadIdx.x >> 6;
    int lo0 = 0, hi0 = n;
    while (lo0 < hi0) { int mid = (lo0 + hi0) >> 1; if (batch[mid] < g) lo0 = mid + 1; else hi0 = mid; }
    int lo1 = lo0, hi1 = n;
    while (lo1 < hi1) { int mid = (lo1 + hi1) >> 1; if (batch[mid] < g + 1) lo1 = mid + 1; else hi1 = mid; }
    float s0 = 0.f, s1 = 0.f;
    int r = lo0 + wv;
    for (; r + 16 < lo1; r += 32) {
        s0 += out2[(size_t)r * 64 + lane];
        s1 += out2[(size_t)(r + 16) * 64 + lane];
    }
    if (r < lo1) s0 += out2[(size_t)r * 64 + lane];
    sbuf[wv][lane] = s0 + s1;
    __syncthreads();
    if (wv == 0) {
        float s = 0.f;
#pragma unroll
        for (int k = 0; k < 16; ++k) s += sbuf[k][lane];
        float cntf = (float)(lo1 - lo0);
        float pooled = s / fmaxf(cntf, 1.f);
        float v = pooled * fcW[lane];
#pragma unroll
        for (int d = 32; d; d >>= 1) v += __shfl_xor(v, d);
        if (lane == 0) out[g] = v + fcb[0];
    }
}

// ---------------- host launcher ----------------
extern "C" void kernel_launch(void* const* d_in, const int* in_sizes, int n_in,
                              void* d_out, int out_size, void* d_ws, size_t ws_size,
                              hipStream_t stream) {
    const float* x      = (const float*)d_in[0];
    const int*   ei     = (const int*)  d_in[1];
    const int*   batch  = (const int*)  d_in[2];
    const float* W1     = (const float*)d_in[3];
    const float* a_src1 = (const float*)d_in[4];
    const float* a_dst1 = (const float*)d_in[5];
    const float* b1     = (const float*)d_in[6];
    const float* W2     = (const float*)d_in[7];
    const float* a_src2 = (const float*)d_in[8];
    const float* a_dst2 = (const float*)d_in[9];
    const float* b2     = (const float*)d_in[10];
    const float* fcW    = (const float*)d_in[11];
    const float* fcb    = (const float*)d_in[12];
    float* out = (float*)d_out;

    const int N = in_sizes[2];
    const int E = in_sizes[1] / 2;
    (void)n_in; (void)ws_size;

    char* ws = (char*)d_ws;
    size_t off = 0;
    auto alloc = [&](size_t bytes) -> char* {
        char* p = ws + off;
        off += (bytes + 255) & ~(size_t)255;
        return p;
    };
    int*    cnt    = (int*)   alloc((size_t)N * 4);
    int*    fill   = (int*)   alloc((size_t)N * 4);
    int*    rowptr = (int*)   alloc((size_t)(N + 1) * 4);
    int*    csr    = (int*)   alloc((size_t)E * 4);
    int*    epos   = (int*)   alloc((size_t)E * 4);
    float*  w1buf  = (float*) alloc((size_t)E * 4 * 4);
    float*  w2buf  = (float*) alloc((size_t)E * 4);
    __half* xh     = (__half*)alloc((size_t)N * 128 * 2);
    __half* W1p    = (__half*)alloc((size_t)128 * 256 * 2);
    __half* W2p    = (__half*)alloc((size_t)256 * 64 * 2);
    __half* h1h    = (__half*)alloc((size_t)N * 256 * 2);
    __half* x2h    = (__half*)alloc((size_t)N * 256 * 2);
    __half* h2h    = (__half*)alloc((size_t)N * 64 * 2);
    float*  out2   = (float*) alloc((size_t)N * 64 * 4);
    float*  als1   = (float*) alloc((size_t)N * 4 * 4);
    float*  ald1   = (float*) alloc((size_t)N * 4 * 4);
    float*  als2   = (float*) alloc((size_t)N * 4);
    float*  ald2   = (float*) alloc((size_t)N * 4);

    hipMemsetAsync(cnt, 0, (size_t)N * 4, stream);
    const int ge = (E + 255) / 256;
    k_hist<<<ge, 256, 0, stream>>>(ei + E, cnt, E);
    k_scan<<<1, 1024, 0, stream>>>(cnt, rowptr, fill, N);
    k_scatter<<<ge, 256, 0, stream>>>(ei, ei + E, fill, csr, epos, E);

    // fp16 conversions / weight packing
    const int n4x = N * 128 / 4;
    k_cvt16<<<(n4x + 255) / 256, 256, 0, stream>>>(x, xh, n4x);
    k_packW<<<(4096 + 255) / 256, 256, 0, stream>>>(W1, W1p, 128, 256);
    k_packW<<<(2048 + 255) / 256, 256, 0, stream>>>(W2, W2p, 256, 64);

    // Layer 1: MFMA GEMM [N,128]@[128,256] -> fp16 h1
    const int gw = (N / 16 + 3) / 4;
    k_gemm_mfma<128, 256><<<gw, 256, 0, stream>>>(xh, W1p, h1h, N);
    const int gn4 = (N + 3) / 4;
    k_al1<<<gn4, 256, 0, stream>>>(h1h, a_src1, a_dst1, als1, ald1, N);
    k_w1<<<ge, 256, 0, stream>>>(ei, ei + E, epos, als1, ald1, w1buf, E);
    k_edge1<<<gn4, 256, 0, stream>>>(h1h, w1buf, als1, ald1, rowptr, csr, b1, x2h, N);

    // Layer 2: MFMA GEMM [N,256]@[256,64] -> fp16 h2
    k_gemm_mfma<256, 64><<<gw, 256, 0, stream>>>(x2h, W2p, h2h, N);
    k_al2<<<gn4, 256, 0, stream>>>(h2h, a_src2, a_dst2, als2, ald2, N);
    k_w2<<<ge, 256, 0, stream>>>(ei, ei + E, epos, als2, ald2, w2buf, E);
    k_edge2<<<gn4, 256, 0, stream>>>(h2h, w2buf, als2, ald2, rowptr, csr, b2, out2, N);

    // Pool + FC
    k_pool<<<out_size, 1024, 0, stream>>>(out2, batch, fcW, fcb, out, N);
}

// Round 7
// 312.578 us; speedup vs baseline: 1.1858x; 1.1858x over previous
//
#include <hip/hip_runtime.h>
#include <hip/hip_fp16.h>
#include <cstddef>
#include <cstdint>

// N=50000, F_IN=128, HID=64, HEADS=4, E=800000, NG=64
// Layer1: x16[N,128]@W1p -> h1(fp16) via MFMA; GAT agg (in-wave cooperative weights) -> x2 fp16
// Layer2: x2@W2p -> h2(fp16) via MFMA; GAT agg -> out2 fp32
// Pool: segment-mean by sorted batch -> [64,64]; fc -> [64]

#define LOG2E 1.4426950408889634f
__device__ __forceinline__ float lrelu02(float x) { return x >= 0.f ? x : 0.2f * x; }
__device__ __forceinline__ float elu1(float x)    { return x > 0.f ? x : expm1f(x); }
__device__ __forceinline__ float fexp(float x)    { return exp2f(x * LOG2E); }

typedef _Float16 f16x8 __attribute__((ext_vector_type(8)));
typedef float    f32x4 __attribute__((ext_vector_type(4)));

// ---------------- CSR build (by destination) ----------------
__global__ void k_hist(const int* __restrict__ dst, int* __restrict__ cnt, int e) {
    int i = blockIdx.x * 256 + threadIdx.x;
    if (i < e) atomicAdd(&cnt[dst[i]], 1);
}

__global__ __launch_bounds__(1024) void k_scan(const int* __restrict__ cnt,
                                               int* __restrict__ rowptr,
                                               int* __restrict__ fill, int n) {
    __shared__ int wsums[16];
    const int t = threadIdx.x, lane = t & 63, wv = t >> 6;
    int carry = 0;
    if (t == 0) rowptr[0] = 0;
    for (int base = 0; base < n; base += 1024) {
        int i = base + t;
        int v = (i < n) ? cnt[i] : 0;
        int s = v;
#pragma unroll
        for (int d = 1; d < 64; d <<= 1) { int o = __shfl_up(s, d); if (lane >= d) s += o; }
        if (lane == 63) wsums[wv] = s;
        __syncthreads();
        if (t < 16) {
            int xx = wsums[t];
#pragma unroll
            for (int d = 1; d < 16; d <<= 1) { int o = __shfl_up(xx, d); if (t >= d) xx += o; }
            wsums[t] = xx;
        }
        __syncthreads();
        int add = carry + (wv > 0 ? wsums[wv - 1] : 0);
        int incl = s + add;
        if (i < n) { rowptr[i + 1] = incl; fill[i] = incl - v; }
        carry += wsums[15];
        __syncthreads();
    }
}

__global__ void k_scatter(const int* __restrict__ src, const int* __restrict__ dstArr,
                          int* __restrict__ fill, int* __restrict__ csr, int e) {
    int i = blockIdx.x * 256 + threadIdx.x;
    if (i < e) {
        int d = dstArr[i];
        int p = atomicAdd(&fill[d], 1);
        csr[p] = src[i];
    }
}

// ---------------- fp32 -> fp16 convert (x) ----------------
__global__ void k_cvt16(const float* __restrict__ in, __half* __restrict__ outp, int n4) {
    int i = blockIdx.x * 256 + threadIdx.x;
    if (i >= n4) return;
    float4 v = *reinterpret_cast<const float4*>(in + (size_t)i * 4);
    __half2 h0 = __floats2half2_rn(v.x, v.y);
    __half2 h1 = __floats2half2_rn(v.z, v.w);
    int2 p;
    p.x = *reinterpret_cast<int*>(&h0);
    p.y = *reinterpret_cast<int*>(&h1);
    *reinterpret_cast<int2*>(outp + (size_t)i * 4) = p;
}

// ---------------- W pack: fp32 [K][N] row-major -> fragment-ordered fp16 ----------------
__global__ void k_packW(const float* __restrict__ W, __half* __restrict__ Bp, int K, int N) {
    int i = blockIdx.x * 256 + threadIdx.x;
    int total = (K / 32) * (N / 16) * 64;
    if (i >= total) return;
    int c = i & 15, q = (i >> 4) & 3, tnt = i >> 6;
    int nt = tnt % (N / 16), t = tnt / (N / 16);
    int k0 = t * 32 + q * 8, col = nt * 16 + c;
    __half tmp[8];
#pragma unroll
    for (int j = 0; j < 8; ++j) tmp[j] = __float2half(W[(size_t)(k0 + j) * N + col]);
    *reinterpret_cast<int4*>(Bp + (size_t)i * 8) = *reinterpret_cast<int4*>(tmp);
}

// ---------------- MFMA GEMM: C[M,N] = A[M,K] @ B[K,N], fp16 in, fp16 out ----------------
template <int K, int N>
__global__ __launch_bounds__(256) void k_gemm_mfma(const __half* __restrict__ A,
                                                   const __half* __restrict__ Bp,
                                                   __half* __restrict__ C, int M) {
    constexpr int NT = N / 16, KT = K / 32;
    const int lane = threadIdx.x & 63;
    const int wv = threadIdx.x >> 6;
    const int row0 = (blockIdx.x * 4 + wv) * 16;
    if (row0 >= M) return;

    f32x4 acc[NT];
#pragma unroll
    for (int nt = 0; nt < NT; ++nt) acc[nt] = (f32x4){0.f, 0.f, 0.f, 0.f};

    const __half* Ab = A + (size_t)(row0 + (lane & 15)) * K + (lane >> 4) * 8;
    const __half* Bb = Bp + (size_t)lane * 8;
#pragma unroll
    for (int t = 0; t < KT; ++t) {
        f16x8 a = *reinterpret_cast<const f16x8*>(Ab + t * 32);
#pragma unroll
        for (int nt = 0; nt < NT; ++nt) {
            f16x8 b = *reinterpret_cast<const f16x8*>(Bb + (size_t)(t * NT + nt) * 512);
            acc[nt] = __builtin_amdgcn_mfma_f32_16x16x32_f16(a, b, acc[nt], 0, 0, 0);
        }
    }
    const int r0 = row0 + (lane >> 4) * 4;
    const int cl = lane & 15;
#pragma unroll
    for (int nt = 0; nt < NT; ++nt) {
        int col = nt * 16 + cl;
#pragma unroll
        for (int j = 0; j < 4; ++j)
            C[(size_t)(r0 + j) * N + col] = __float2half(acc[nt][j]);
    }
}

__device__ __forceinline__ void load_h4(const __half* __restrict__ p, float2& lo, float2& hi) {
    float2 raw = *reinterpret_cast<const float2*>(p);   // 8B = 4 halves
    __half2* q = reinterpret_cast<__half2*>(&raw);
    lo = __half22float2(q[0]);
    hi = __half22float2(q[1]);
}

// ---------------- attention logits, layer 1 ----------------
__global__ void k_al1(const __half* __restrict__ h1, const float* __restrict__ a_src,
                      const float* __restrict__ a_dst, float* __restrict__ als,
                      float* __restrict__ ald, int n) {
    const int lane = threadIdx.x & 63;
    const int node = (blockIdx.x << 2) + (threadIdx.x >> 6);
    if (node >= n) return;
    const int head = lane >> 4;
    float2 lo, hi;
    load_h4(h1 + (size_t)node * 256 + lane * 4, lo, hi);
    float4 av = *reinterpret_cast<const float4*>(a_src + lane * 4);
    float4 dv = *reinterpret_cast<const float4*>(a_dst + lane * 4);
    float ps = lo.x * av.x + lo.y * av.y + hi.x * av.z + hi.y * av.w;
    float pd = lo.x * dv.x + lo.y * dv.y + hi.x * dv.z + hi.y * dv.w;
#pragma unroll
    for (int d = 1; d < 16; d <<= 1) { ps += __shfl_xor(ps, d); pd += __shfl_xor(pd, d); }
    if ((lane & 15) == 0) { als[node * 4 + head] = ps; ald[node * 4 + head] = pd; }
}

// ---------------- edge aggregation, layer 1 ----------------
// 4 edges/iter; the 16 distinct (edge,head) weights are computed once
// (lane l -> edge l&3, head (l>>2)&3) and redistributed with 4 shuffles.
__global__ void k_edge1(const __half* __restrict__ h1, const float* __restrict__ als,
                        const float* __restrict__ ald, const int* __restrict__ rowptr,
                        const int* __restrict__ csr, const float* __restrict__ b1,
                        __half* __restrict__ x2, int n) {
    const int lane = threadIdx.x & 63;
    const int node = (blockIdx.x << 2) + (threadIdx.x >> 6);
    if (node >= n) return;
    const int head = lane >> 4;
    const int ch = lane * 4;
    const int e4 = lane & 3, h4 = (lane >> 2) & 3;
    const float adh  = ald[node * 4 + head];   // own head (remainder + self-loop)
    const float adh4 = ald[node * 4 + h4];     // weight-duty head (hoisted)
    const int wsrc = head << 2;
    float ax = 0.f, ay = 0.f, az = 0.f, aw = 0.f, wsum = 0.f;
    const int beg = rowptr[node], end = rowptr[node + 1];
    int i = beg;
    for (; i + 4 <= end; i += 4) {
        int s0 = csr[i], s1 = csr[i + 1], s2 = csr[i + 2], s3 = csr[i + 3];
        int se = e4 == 0 ? s0 : e4 == 1 ? s1 : e4 == 2 ? s2 : s3;
        float myw = fexp(lrelu02(als[se * 4 + h4] + adh4));
        float w0 = __shfl(myw, wsrc);
        float w1 = __shfl(myw, wsrc + 1);
        float w2 = __shfl(myw, wsrc + 2);
        float w3 = __shfl(myw, wsrc + 3);
        float2 l0, u0, l1, u1, l2, u2, l3, u3;
        load_h4(h1 + (size_t)s0 * 256 + ch, l0, u0);
        load_h4(h1 + (size_t)s1 * 256 + ch, l1, u1);
        load_h4(h1 + (size_t)s2 * 256 + ch, l2, u2);
        load_h4(h1 + (size_t)s3 * 256 + ch, l3, u3);
        ax += w0 * l0.x + w1 * l1.x + w2 * l2.x + w3 * l3.x;
        ay += w0 * l0.y + w1 * l1.y + w2 * l2.y + w3 * l3.y;
        az += w0 * u0.x + w1 * u1.x + w2 * u2.x + w3 * u3.x;
        aw += w0 * u0.y + w1 * u1.y + w2 * u2.y + w3 * u3.y;
        wsum += (w0 + w1) + (w2 + w3);
    }
    for (; i < end; ++i) {
        int s0 = csr[i];
        float w0 = fexp(lrelu02(als[s0 * 4 + head] + adh));
        float2 l0, u0;
        load_h4(h1 + (size_t)s0 * 256 + ch, l0, u0);
        ax += w0 * l0.x; ay += w0 * l0.y; az += w0 * u0.x; aw += w0 * u0.y;
        wsum += w0;
    }
    {   // self loop
        float w0 = fexp(lrelu02(als[node * 4 + head] + adh));
        float2 l0, u0;
        load_h4(h1 + (size_t)node * 256 + ch, l0, u0);
        ax += w0 * l0.x; ay += w0 * l0.y; az += w0 * u0.x; aw += w0 * u0.y;
        wsum += w0;
    }
    const float inv = 1.f / (wsum + 1e-16f);
    float4 bv = *reinterpret_cast<const float4*>(b1 + ch);
    __half2 r0 = __floats2half2_rn(elu1(ax * inv + bv.x), elu1(ay * inv + bv.y));
    __half2 r1 = __floats2half2_rn(elu1(az * inv + bv.z), elu1(aw * inv + bv.w));
    int2 p;
    p.x = *reinterpret_cast<int*>(&r0);
    p.y = *reinterpret_cast<int*>(&r1);
    *reinterpret_cast<int2*>(x2 + (size_t)node * 256 + ch) = p;
}

// ---------------- attention logits, layer 2 ----------------
__global__ void k_al2(const __half* __restrict__ h2, const float* __restrict__ a_src,
                      const float* __restrict__ a_dst, float* __restrict__ als,
                      float* __restrict__ ald, int n) {
    const int lane = threadIdx.x & 63;
    const int node = (blockIdx.x << 2) + (threadIdx.x >> 6);
    if (node >= n) return;
    float hv = __half2float(h2[(size_t)node * 64 + lane]);
    float ps = hv * a_src[lane];
    float pd = hv * a_dst[lane];
#pragma unroll
    for (int d = 1; d < 64; d <<= 1) { ps += __shfl_xor(ps, d); pd += __shfl_xor(pd, d); }
    if (lane == 0) { als[node] = ps; ald[node] = pd; }
}

// ---------------- edge aggregation, layer 2 ----------------
// 8 edges/iter; lane l computes the weight of edge l&7 (8 distinct exps per wave),
// weights and src indices redistributed with compile-time-source shuffles.
__global__ void k_edge2(const __half* __restrict__ h2, const float* __restrict__ als,
                        const float* __restrict__ ald, const int* __restrict__ rowptr,
                        const int* __restrict__ csr, const float* __restrict__ b2,
                        float* __restrict__ out2, int n) {
    const int lane = threadIdx.x & 63;
    const int node = (blockIdx.x << 2) + (threadIdx.x >> 6);
    if (node >= n) return;
    const float adl = ald[node];
    float acc = 0.f, wsum = 0.f;
    const int beg = rowptr[node], end = rowptr[node + 1];
    int i = beg;
    for (; i + 8 <= end; i += 8) {
        int se = csr[i + (lane & 7)];
        float myw = fexp(lrelu02(als[se] + adl));
        int   s0 = __shfl(se, 0), s1 = __shfl(se, 1), s2 = __shfl(se, 2), s3 = __shfl(se, 3);
        int   s4 = __shfl(se, 4), s5 = __shfl(se, 5), s6 = __shfl(se, 6), s7 = __shfl(se, 7);
        float w0 = __shfl(myw, 0), w1 = __shfl(myw, 1), w2 = __shfl(myw, 2), w3 = __shfl(myw, 3);
        float w4 = __shfl(myw, 4), w5 = __shfl(myw, 5), w6 = __shfl(myw, 6), w7 = __shfl(myw, 7);
        float v0 = __half2float(h2[(size_t)s0 * 64 + lane]);
        float v1 = __half2float(h2[(size_t)s1 * 64 + lane]);
        float v2 = __half2float(h2[(size_t)s2 * 64 + lane]);
        float v3 = __half2float(h2[(size_t)s3 * 64 + lane]);
        float v4 = __half2float(h2[(size_t)s4 * 64 + lane]);
        float v5 = __half2float(h2[(size_t)s5 * 64 + lane]);
        float v6 = __half2float(h2[(size_t)s6 * 64 + lane]);
        float v7 = __half2float(h2[(size_t)s7 * 64 + lane]);
        acc += (w0 * v0 + w1 * v1) + (w2 * v2 + w3 * v3)
             + (w4 * v4 + w5 * v5) + (w6 * v6 + w7 * v7);
        wsum += (w0 + w1 + w2 + w3) + (w4 + w5 + w6 + w7);
    }
    for (; i < end; ++i) {
        int s0 = csr[i];
        float w0 = fexp(lrelu02(als[s0] + adl));
        acc += w0 * __half2float(h2[(size_t)s0 * 64 + lane]);
        wsum += w0;
    }
    {   // self loop
        float w0 = fexp(lrelu02(als[node] + adl));
        acc += w0 * __half2float(h2[(size_t)node * 64 + lane]);
        wsum += w0;
    }
    float o = acc / (wsum + 1e-16f) + b2[lane];
    out2[(size_t)node * 64 + lane] = elu1(o);
}

// ---------------- pool (mean by sorted batch) + fc ----------------
__global__ __launch_bounds__(1024) void k_pool(const float* __restrict__ out2,
                                               const int* __restrict__ batch,
                                               const float* __restrict__ fcW,
                                               const float* __restrict__ fcb,
                                               float* __restrict__ out, int n) {
    __shared__ float sbuf[16][64];
    const int g = blockIdx.x;
    const int lane = threadIdx.x & 63, wv = threadIdx.x >> 6;
    int lo0 = 0, hi0 = n;
    while (lo0 < hi0) { int mid = (lo0 + hi0) >> 1; if (batch[mid] < g) lo0 = mid + 1; else hi0 = mid; }
    int lo1 = lo0, hi1 = n;
    while (lo1 < hi1) { int mid = (lo1 + hi1) >> 1; if (batch[mid] < g + 1) lo1 = mid + 1; else hi1 = mid; }
    float s0 = 0.f, s1 = 0.f;
    int r = lo0 + wv;
    for (; r + 16 < lo1; r += 32) {
        s0 += out2[(size_t)r * 64 + lane];
        s1 += out2[(size_t)(r + 16) * 64 + lane];
    }
    if (r < lo1) s0 += out2[(size_t)r * 64 + lane];
    sbuf[wv][lane] = s0 + s1;
    __syncthreads();
    if (wv == 0) {
        float s = 0.f;
#pragma unroll
        for (int k = 0; k < 16; ++k) s += sbuf[k][lane];
        float cntf = (float)(lo1 - lo0);
        float pooled = s / fmaxf(cntf, 1.f);
        float v = pooled * fcW[lane];
#pragma unroll
        for (int d = 32; d; d >>= 1) v += __shfl_xor(v, d);
        if (lane == 0) out[g] = v + fcb[0];
    }
}

// ---------------- host launcher ----------------
extern "C" void kernel_launch(void* const* d_in, const int* in_sizes, int n_in,
                              void* d_out, int out_size, void* d_ws, size_t ws_size,
                              hipStream_t stream) {
    const float* x      = (const float*)d_in[0];
    const int*   ei     = (const int*)  d_in[1];
    const int*   batch  = (const int*)  d_in[2];
    const float* W1     = (const float*)d_in[3];
    const float* a_src1 = (const float*)d_in[4];
    const float* a_dst1 = (const float*)d_in[5];
    const float* b1     = (const float*)d_in[6];
    const float* W2     = (const float*)d_in[7];
    const float* a_src2 = (const float*)d_in[8];
    const float* a_dst2 = (const float*)d_in[9];
    const float* b2     = (const float*)d_in[10];
    const float* fcW    = (const float*)d_in[11];
    const float* fcb    = (const float*)d_in[12];
    float* out = (float*)d_out;

    const int N = in_sizes[2];
    const int E = in_sizes[1] / 2;
    (void)n_in; (void)ws_size;

    char* ws = (char*)d_ws;
    size_t off = 0;
    auto alloc = [&](size_t bytes) -> char* {
        char* p = ws + off;
        off += (bytes + 255) & ~(size_t)255;
        return p;
    };
    int*    cnt    = (int*)   alloc((size_t)N * 4);
    int*    fill   = (int*)   alloc((size_t)N * 4);
    int*    rowptr = (int*)   alloc((size_t)(N + 1) * 4);
    int*    csr    = (int*)   alloc((size_t)E * 4);
    __half* xh     = (__half*)alloc((size_t)N * 128 * 2);
    __half* W1p    = (__half*)alloc((size_t)128 * 256 * 2);
    __half* W2p    = (__half*)alloc((size_t)256 * 64 * 2);
    __half* h1h    = (__half*)alloc((size_t)N * 256 * 2);
    __half* x2h    = (__half*)alloc((size_t)N * 256 * 2);
    __half* h2h    = (__half*)alloc((size_t)N * 64 * 2);
    float*  out2   = (float*) alloc((size_t)N * 64 * 4);
    float*  als1   = (float*) alloc((size_t)N * 4 * 4);
    float*  ald1   = (float*) alloc((size_t)N * 4 * 4);
    float*  als2   = (float*) alloc((size_t)N * 4);
    float*  ald2   = (float*) alloc((size_t)N * 4);

    hipMemsetAsync(cnt, 0, (size_t)N * 4, stream);
    const int ge = (E + 255) / 256;
    k_hist<<<ge, 256, 0, stream>>>(ei + E, cnt, E);
    k_scan<<<1, 1024, 0, stream>>>(cnt, rowptr, fill, N);
    k_scatter<<<ge, 256, 0, stream>>>(ei, ei + E, fill, csr, E);

    // fp16 conversions / weight packing
    const int n4x = N * 128 / 4;
    k_cvt16<<<(n4x + 255) / 256, 256, 0, stream>>>(x, xh, n4x);
    k_packW<<<(4096 + 255) / 256, 256, 0, stream>>>(W1, W1p, 128, 256);
    k_packW<<<(2048 + 255) / 256, 256, 0, stream>>>(W2, W2p, 256, 64);

    // Layer 1: MFMA GEMM [N,128]@[128,256] -> fp16 h1
    const int gw = (N / 16 + 3) / 4;
    k_gemm_mfma<128, 256><<<gw, 256, 0, stream>>>(xh, W1p, h1h, N);
    const int gn4 = (N + 3) / 4;
    k_al1<<<gn4, 256, 0, stream>>>(h1h, a_src1, a_dst1, als1, ald1, N);
    k_edge1<<<gn4, 256, 0, stream>>>(h1h, als1, ald1, rowptr, csr, b1, x2h, N);

    // Layer 2: MFMA GEMM [N,256]@[256,64] -> fp16 h2
    k_gemm_mfma<256, 64><<<gw, 256, 0, stream>>>(x2h, W2p, h2h, N);
    k_al2<<<gn4, 256, 0, stream>>>(h2h, a_src2, a_dst2, als2, ald2, N);
    k_edge2<<<gn4, 256, 0, stream>>>(h2h, als2, ald2, rowptr, csr, b2, out2, N);

    // Pool + FC
    k_pool<<<out_size, 1024, 0, stream>>>(out2, batch, fcW, fcb, out, N);
}

// Round 8
// 244.811 us; speedup vs baseline: 1.5141x; 1.2768x over previous
//
#include <hip/hip_runtime.h>
#include <hip/hip_fp16.h>
#include <cstddef>
#include <cstdint>

// N=50000, F_IN=128, HID=64, HEADS=4, E=800000, NG=64
// Layer1: x16[N,128]@W1p -> h1(fp16) via MFMA; GAT agg (8-wide, in-wave weights) -> x2 fp16
// Layer2: x2@W2p -> h2(fp16) via MFMA; GAT agg -> out2 fp32
// Pool: segment-mean by sorted batch -> [64,64]; fc -> [64]

#define LOG2E 1.4426950408889634f
__device__ __forceinline__ float lrelu02(float x) { return x >= 0.f ? x : 0.2f * x; }
__device__ __forceinline__ float elu1(float x)    { return x > 0.f ? x : expm1f(x); }
__device__ __forceinline__ float fexp(float x)    { return exp2f(x * LOG2E); }

typedef _Float16 f16x8 __attribute__((ext_vector_type(8)));
typedef float    f32x4 __attribute__((ext_vector_type(4)));

// ---------------- CSR build (by destination) ----------------
// Pass 1: histogram + per-edge rank (one atomic pass total)
__global__ void k_hist(const int* __restrict__ dst, int* __restrict__ cnt,
                       int* __restrict__ rank, int e) {
    int i = blockIdx.x * 256 + threadIdx.x;
    if (i < e) rank[i] = atomicAdd(&cnt[dst[i]], 1);
}

// Parallel hierarchical scan: per-block inclusive scan + block sums
__global__ __launch_bounds__(1024) void k_scan1(const int* __restrict__ cnt,
                                                int* __restrict__ cscan,
                                                int* __restrict__ bsum, int n) {
    __shared__ int ws[16];
    const int t = threadIdx.x, lane = t & 63, wv = t >> 6;
    const int i = blockIdx.x * 1024 + t;
    int v = (i < n) ? cnt[i] : 0;
    int s = v;
#pragma unroll
    for (int d = 1; d < 64; d <<= 1) { int o = __shfl_up(s, d); if (lane >= d) s += o; }
    if (lane == 63) ws[wv] = s;
    __syncthreads();
    if (t < 16) {
        int xx = ws[t];
#pragma unroll
        for (int d = 1; d < 16; d <<= 1) { int o = __shfl_up(xx, d); if (t >= d) xx += o; }
        ws[t] = xx;
        if (t == 15) bsum[blockIdx.x] = xx;
    }
    __syncthreads();
    int incl = s + (wv > 0 ? ws[wv - 1] : 0);
    if (i < n) cscan[i] = incl;
}

// scan of block sums (nb <= 1024), in-place -> exclusive prefix
__global__ __launch_bounds__(1024) void k_scan2(int* __restrict__ bsum, int nb) {
    __shared__ int ws[16];
    const int t = threadIdx.x, lane = t & 63, wv = t >> 6;
    int v = (t < nb) ? bsum[t] : 0;
    int s = v;
#pragma unroll
    for (int d = 1; d < 64; d <<= 1) { int o = __shfl_up(s, d); if (lane >= d) s += o; }
    if (lane == 63) ws[wv] = s;
    __syncthreads();
    if (t < 16) {
        int xx = ws[t];
#pragma unroll
        for (int d = 1; d < 16; d <<= 1) { int o = __shfl_up(xx, d); if (t >= d) xx += o; }
        ws[t] = xx;
    }
    __syncthreads();
    int incl = s + (wv > 0 ? ws[wv - 1] : 0);
    if (t < nb) bsum[t] = incl - v;   // exclusive
}

__global__ __launch_bounds__(1024) void k_scan3(const int* __restrict__ cscan,
                                                const int* __restrict__ bsum,
                                                int* __restrict__ rowptr, int n) {
    const int i = blockIdx.x * 1024 + threadIdx.x;
    if (i < n) rowptr[i + 1] = cscan[i] + bsum[blockIdx.x];
    if (i == 0) rowptr[0] = 0;
}

// Pass 2: no atomics — slot = rowptr[dst] + rank
__global__ void k_scatter(const int* __restrict__ src, const int* __restrict__ dstArr,
                          const int* __restrict__ rank, const int* __restrict__ rowptr,
                          int* __restrict__ csr, int e) {
    int i = blockIdx.x * 256 + threadIdx.x;
    if (i < e) csr[rowptr[dstArr[i]] + rank[i]] = src[i];
}

// ---------------- fp32 -> fp16 convert (x) ----------------
__global__ void k_cvt16(const float* __restrict__ in, __half* __restrict__ outp, int n4) {
    int i = blockIdx.x * 256 + threadIdx.x;
    if (i >= n4) return;
    float4 v = *reinterpret_cast<const float4*>(in + (size_t)i * 4);
    __half2 h0 = __floats2half2_rn(v.x, v.y);
    __half2 h1 = __floats2half2_rn(v.z, v.w);
    int2 p;
    p.x = *reinterpret_cast<int*>(&h0);
    p.y = *reinterpret_cast<int*>(&h1);
    *reinterpret_cast<int2*>(outp + (size_t)i * 4) = p;
}

// ---------------- W pack: fp32 [K][N] row-major -> fragment-ordered fp16 ----------------
__global__ void k_packW(const float* __restrict__ W, __half* __restrict__ Bp, int K, int N) {
    int i = blockIdx.x * 256 + threadIdx.x;
    int total = (K / 32) * (N / 16) * 64;
    if (i >= total) return;
    int c = i & 15, q = (i >> 4) & 3, tnt = i >> 6;
    int nt = tnt % (N / 16), t = tnt / (N / 16);
    int k0 = t * 32 + q * 8, col = nt * 16 + c;
    __half tmp[8];
#pragma unroll
    for (int j = 0; j < 8; ++j) tmp[j] = __float2half(W[(size_t)(k0 + j) * N + col]);
    *reinterpret_cast<int4*>(Bp + (size_t)i * 8) = *reinterpret_cast<int4*>(tmp);
}

// ---------------- MFMA GEMM: C[M,N] = A[M,K] @ B[K,N], fp16 in, fp16 out ----------------
template <int K, int N>
__global__ __launch_bounds__(256) void k_gemm_mfma(const __half* __restrict__ A,
                                                   const __half* __restrict__ Bp,
                                                   __half* __restrict__ C, int M) {
    constexpr int NT = N / 16, KT = K / 32;
    const int lane = threadIdx.x & 63;
    const int wv = threadIdx.x >> 6;
    const int row0 = (blockIdx.x * 4 + wv) * 16;
    if (row0 >= M) return;

    f32x4 acc[NT];
#pragma unroll
    for (int nt = 0; nt < NT; ++nt) acc[nt] = (f32x4){0.f, 0.f, 0.f, 0.f};

    const __half* Ab = A + (size_t)(row0 + (lane & 15)) * K + (lane >> 4) * 8;
    const __half* Bb = Bp + (size_t)lane * 8;
#pragma unroll
    for (int t = 0; t < KT; ++t) {
        f16x8 a = *reinterpret_cast<const f16x8*>(Ab + t * 32);
#pragma unroll
        for (int nt = 0; nt < NT; ++nt) {
            f16x8 b = *reinterpret_cast<const f16x8*>(Bb + (size_t)(t * NT + nt) * 512);
            acc[nt] = __builtin_amdgcn_mfma_f32_16x16x32_f16(a, b, acc[nt], 0, 0, 0);
        }
    }
    const int r0 = row0 + (lane >> 4) * 4;
    const int cl = lane & 15;
#pragma unroll
    for (int nt = 0; nt < NT; ++nt) {
        int col = nt * 16 + cl;
#pragma unroll
        for (int j = 0; j < 4; ++j)
            C[(size_t)(r0 + j) * N + col] = __float2half(acc[nt][j]);
    }
}

__device__ __forceinline__ void load_h4(const __half* __restrict__ p, float2& lo, float2& hi) {
    float2 raw = *reinterpret_cast<const float2*>(p);   // 8B = 4 halves
    __half2* q = reinterpret_cast<__half2*>(&raw);
    lo = __half22float2(q[0]);
    hi = __half22float2(q[1]);
}

__device__ __forceinline__ void h4acc(float2 raw, float w, float& ax, float& ay,
                                      float& az, float& aw2) {
    __half2* q = reinterpret_cast<__half2*>(&raw);
    float2 lo = __half22float2(q[0]), hi = __half22float2(q[1]);
    ax = fmaf(w, lo.x, ax); ay = fmaf(w, lo.y, ay);
    az = fmaf(w, hi.x, az); aw2 = fmaf(w, hi.y, aw2);
}

// ---------------- attention logits, layer 1 ----------------
__global__ void k_al1(const __half* __restrict__ h1, const float* __restrict__ a_src,
                      const float* __restrict__ a_dst, float* __restrict__ als,
                      float* __restrict__ ald, int n) {
    const int lane = threadIdx.x & 63;
    const int node = (blockIdx.x << 2) + (threadIdx.x >> 6);
    if (node >= n) return;
    const int head = lane >> 4;
    float2 lo, hi;
    load_h4(h1 + (size_t)node * 256 + lane * 4, lo, hi);
    float4 av = *reinterpret_cast<const float4*>(a_src + lane * 4);
    float4 dv = *reinterpret_cast<const float4*>(a_dst + lane * 4);
    float ps = lo.x * av.x + lo.y * av.y + hi.x * av.z + hi.y * av.w;
    float pd = lo.x * dv.x + lo.y * dv.y + hi.x * dv.z + hi.y * dv.w;
#pragma unroll
    for (int d = 1; d < 16; d <<= 1) { ps += __shfl_xor(ps, d); pd += __shfl_xor(pd, d); }
    if ((lane & 15) == 0) { als[node * 4 + head] = ps; ald[node * 4 + head] = pd; }
}

// ---------------- edge aggregation, layer 1 ----------------
// 8 edges/iter. Lane l computes the weight of (edge l&7, head (l>>3)&3) — the 32
// distinct (edge,head) weights are computed once and redistributed with shuffles.
// Src indices broadcast via compile-time-lane shuffles (-> SGPR base addressing).
__global__ void k_edge1(const __half* __restrict__ h1, const float* __restrict__ als,
                        const float* __restrict__ ald, const int* __restrict__ rowptr,
                        const int* __restrict__ csr, const float* __restrict__ b1,
                        __half* __restrict__ x2, int n) {
    const int lane = threadIdx.x & 63;
    const int node = (blockIdx.x << 2) + (threadIdx.x >> 6);
    if (node >= n) return;
    const int head = lane >> 4;
    const int ch = lane * 4;
    const int e8 = lane & 7, h8 = (lane >> 3) & 3;
    const float adh  = ald[node * 4 + head];   // own head (remainder + self-loop)
    const float adh8 = ald[node * 4 + h8];     // weight-duty head (hoisted)
    const int wb = head << 3;
    float axA = 0.f, ayA = 0.f, azA = 0.f, awA = 0.f;
    float axB = 0.f, ayB = 0.f, azB = 0.f, awB = 0.f;
    float wsum = 0.f;
    const int beg = rowptr[node], end = rowptr[node + 1];
    int i = beg;
    for (; i + 8 <= end; i += 8) {
        int se = csr[i + e8];
        float myw = fexp(lrelu02(als[se * 4 + h8] + adh8));
        int s0 = __shfl(se, 0), s1 = __shfl(se, 1), s2 = __shfl(se, 2), s3 = __shfl(se, 3);
        int s4 = __shfl(se, 4), s5 = __shfl(se, 5), s6 = __shfl(se, 6), s7 = __shfl(se, 7);
        float w0 = __shfl(myw, wb + 0), w1 = __shfl(myw, wb + 1);
        float w2 = __shfl(myw, wb + 2), w3 = __shfl(myw, wb + 3);
        float w4 = __shfl(myw, wb + 4), w5 = __shfl(myw, wb + 5);
        float w6 = __shfl(myw, wb + 6), w7 = __shfl(myw, wb + 7);
        float2 r0 = *reinterpret_cast<const float2*>(h1 + (size_t)s0 * 256 + ch);
        float2 r1 = *reinterpret_cast<const float2*>(h1 + (size_t)s1 * 256 + ch);
        float2 r2 = *reinterpret_cast<const float2*>(h1 + (size_t)s2 * 256 + ch);
        float2 r3 = *reinterpret_cast<const float2*>(h1 + (size_t)s3 * 256 + ch);
        float2 r4 = *reinterpret_cast<const float2*>(h1 + (size_t)s4 * 256 + ch);
        float2 r5 = *reinterpret_cast<const float2*>(h1 + (size_t)s5 * 256 + ch);
        float2 r6 = *reinterpret_cast<const float2*>(h1 + (size_t)s6 * 256 + ch);
        float2 r7 = *reinterpret_cast<const float2*>(h1 + (size_t)s7 * 256 + ch);
        h4acc(r0, w0, axA, ayA, azA, awA);
        h4acc(r1, w1, axB, ayB, azB, awB);
        h4acc(r2, w2, axA, ayA, azA, awA);
        h4acc(r3, w3, axB, ayB, azB, awB);
        h4acc(r4, w4, axA, ayA, azA, awA);
        h4acc(r5, w5, axB, ayB, azB, awB);
        h4acc(r6, w6, axA, ayA, azA, awA);
        h4acc(r7, w7, axB, ayB, azB, awB);
        wsum += ((w0 + w1) + (w2 + w3)) + ((w4 + w5) + (w6 + w7));
    }
    float ax = axA + axB, ay = ayA + ayB, az = azA + azB, aw = awA + awB;
    for (; i < end; ++i) {
        int s0 = csr[i];
        float w0 = fexp(lrelu02(als[s0 * 4 + head] + adh));
        float2 l0, u0;
        load_h4(h1 + (size_t)s0 * 256 + ch, l0, u0);
        ax += w0 * l0.x; ay += w0 * l0.y; az += w0 * u0.x; aw += w0 * u0.y;
        wsum += w0;
    }
    {   // self loop
        float w0 = fexp(lrelu02(als[node * 4 + head] + adh));
        float2 l0, u0;
        load_h4(h1 + (size_t)node * 256 + ch, l0, u0);
        ax += w0 * l0.x; ay += w0 * l0.y; az += w0 * u0.x; aw += w0 * u0.y;
        wsum += w0;
    }
    const float inv = 1.f / (wsum + 1e-16f);
    float4 bv = *reinterpret_cast<const float4*>(b1 + ch);
    __half2 r0 = __floats2half2_rn(elu1(ax * inv + bv.x), elu1(ay * inv + bv.y));
    __half2 r1 = __floats2half2_rn(elu1(az * inv + bv.z), elu1(aw * inv + bv.w));
    int2 p;
    p.x = *reinterpret_cast<int*>(&r0);
    p.y = *reinterpret_cast<int*>(&r1);
    *reinterpret_cast<int2*>(x2 + (size_t)node * 256 + ch) = p;
}

// ---------------- attention logits, layer 2 ----------------
__global__ void k_al2(const __half* __restrict__ h2, const float* __restrict__ a_src,
                      const float* __restrict__ a_dst, float* __restrict__ als,
                      float* __restrict__ ald, int n) {
    const int lane = threadIdx.x & 63;
    const int node = (blockIdx.x << 2) + (threadIdx.x >> 6);
    if (node >= n) return;
    float hv = __half2float(h2[(size_t)node * 64 + lane]);
    float ps = hv * a_src[lane];
    float pd = hv * a_dst[lane];
#pragma unroll
    for (int d = 1; d < 64; d <<= 1) { ps += __shfl_xor(ps, d); pd += __shfl_xor(pd, d); }
    if (lane == 0) { als[node] = ps; ald[node] = pd; }
}

// ---------------- edge aggregation, layer 2 ----------------
__global__ void k_edge2(const __half* __restrict__ h2, const float* __restrict__ als,
                        const float* __restrict__ ald, const int* __restrict__ rowptr,
                        const int* __restrict__ csr, const float* __restrict__ b2,
                        float* __restrict__ out2, int n) {
    const int lane = threadIdx.x & 63;
    const int node = (blockIdx.x << 2) + (threadIdx.x >> 6);
    if (node >= n) return;
    const float adl = ald[node];
    float acc = 0.f, wsum = 0.f;
    const int beg = rowptr[node], end = rowptr[node + 1];
    int i = beg;
    for (; i + 8 <= end; i += 8) {
        int se = csr[i + (lane & 7)];
        float myw = fexp(lrelu02(als[se] + adl));
        int   s0 = __shfl(se, 0), s1 = __shfl(se, 1), s2 = __shfl(se, 2), s3 = __shfl(se, 3);
        int   s4 = __shfl(se, 4), s5 = __shfl(se, 5), s6 = __shfl(se, 6), s7 = __shfl(se, 7);
        float w0 = __shfl(myw, 0), w1 = __shfl(myw, 1), w2 = __shfl(myw, 2), w3 = __shfl(myw, 3);
        float w4 = __shfl(myw, 4), w5 = __shfl(myw, 5), w6 = __shfl(myw, 6), w7 = __shfl(myw, 7);
        float v0 = __half2float(h2[(size_t)s0 * 64 + lane]);
        float v1 = __half2float(h2[(size_t)s1 * 64 + lane]);
        float v2 = __half2float(h2[(size_t)s2 * 64 + lane]);
        float v3 = __half2float(h2[(size_t)s3 * 64 + lane]);
        float v4 = __half2float(h2[(size_t)s4 * 64 + lane]);
        float v5 = __half2float(h2[(size_t)s5 * 64 + lane]);
        float v6 = __half2float(h2[(size_t)s6 * 64 + lane]);
        float v7 = __half2float(h2[(size_t)s7 * 64 + lane]);
        acc += (w0 * v0 + w1 * v1) + (w2 * v2 + w3 * v3)
             + (w4 * v4 + w5 * v5) + (w6 * v6 + w7 * v7);
        wsum += (w0 + w1 + w2 + w3) + (w4 + w5 + w6 + w7);
    }
    for (; i < end; ++i) {
        int s0 = csr[i];
        float w0 = fexp(lrelu02(als[s0] + adl));
        acc += w0 * __half2float(h2[(size_t)s0 * 64 + lane]);
        wsum += w0;
    }
    {   // self loop
        float w0 = fexp(lrelu02(als[node] + adl));
        acc += w0 * __half2float(h2[(size_t)node * 64 + lane]);
        wsum += w0;
    }
    float o = acc / (wsum + 1e-16f) + b2[lane];
    out2[(size_t)node * 64 + lane] = elu1(o);
}

// ---------------- pool (mean by sorted batch) + fc ----------------
__global__ __launch_bounds__(1024) void k_pool(const float* __restrict__ out2,
                                               const int* __restrict__ batch,
                                               const float* __restrict__ fcW,
                                               const float* __restrict__ fcb,
                                               float* __restrict__ out, int n) {
    __shared__ float sbuf[16][64];
    const int g = blockIdx.x;
    const int lane = threadIdx.x & 63, wv = threadIdx.x >> 6;
    int lo0 = 0, hi0 = n;
    while (lo0 < hi0) { int mid = (lo0 + hi0) >> 1; if (batch[mid] < g) lo0 = mid + 1; else hi0 = mid; }
    int lo1 = lo0, hi1 = n;
    while (lo1 < hi1) { int mid = (lo1 + hi1) >> 1; if (batch[mid] < g + 1) lo1 = mid + 1; else hi1 = mid; }
    float s0 = 0.f, s1 = 0.f;
    int r = lo0 + wv;
    for (; r + 16 < lo1; r += 32) {
        s0 += out2[(size_t)r * 64 + lane];
        s1 += out2[(size_t)(r + 16) * 64 + lane];
    }
    if (r < lo1) s0 += out2[(size_t)r * 64 + lane];
    sbuf[wv][lane] = s0 + s1;
    __syncthreads();
    if (wv == 0) {
        float s = 0.f;
#pragma unroll
        for (int k = 0; k < 16; ++k) s += sbuf[k][lane];
        float cntf = (float)(lo1 - lo0);
        float pooled = s / fmaxf(cntf, 1.f);
        float v = pooled * fcW[lane];
#pragma unroll
        for (int d = 32; d; d >>= 1) v += __shfl_xor(v, d);
        if (lane == 0) out[g] = v + fcb[0];
    }
}

// ---------------- host launcher ----------------
extern "C" void kernel_launch(void* const* d_in, const int* in_sizes, int n_in,
                              void* d_out, int out_size, void* d_ws, size_t ws_size,
                              hipStream_t stream) {
    const float* x      = (const float*)d_in[0];
    const int*   ei     = (const int*)  d_in[1];
    const int*   batch  = (const int*)  d_in[2];
    const float* W1     = (const float*)d_in[3];
    const float* a_src1 = (const float*)d_in[4];
    const float* a_dst1 = (const float*)d_in[5];
    const float* b1     = (const float*)d_in[6];
    const float* W2     = (const float*)d_in[7];
    const float* a_src2 = (const float*)d_in[8];
    const float* a_dst2 = (const float*)d_in[9];
    const float* b2     = (const float*)d_in[10];
    const float* fcW    = (const float*)d_in[11];
    const float* fcb    = (const float*)d_in[12];
    float* out = (float*)d_out;

    const int N = in_sizes[2];
    const int E = in_sizes[1] / 2;
    (void)n_in; (void)ws_size;

    char* ws = (char*)d_ws;
    size_t off = 0;
    auto alloc = [&](size_t bytes) -> char* {
        char* p = ws + off;
        off += (bytes + 255) & ~(size_t)255;
        return p;
    };
    int*    cnt    = (int*)   alloc((size_t)N * 4);
    int*    cscan  = (int*)   alloc((size_t)N * 4);
    int*    bsum   = (int*)   alloc((size_t)1024 * 4);
    int*    rank   = (int*)   alloc((size_t)E * 4);
    int*    rowptr = (int*)   alloc((size_t)(N + 1) * 4);
    int*    csr    = (int*)   alloc((size_t)E * 4);
    __half* xh     = (__half*)alloc((size_t)N * 128 * 2);
    __half* W1p    = (__half*)alloc((size_t)128 * 256 * 2);
    __half* W2p    = (__half*)alloc((size_t)256 * 64 * 2);
    __half* h1h    = (__half*)alloc((size_t)N * 256 * 2);
    __half* x2h    = (__half*)alloc((size_t)N * 256 * 2);
    __half* h2h    = (__half*)alloc((size_t)N * 64 * 2);
    float*  out2   = (float*) alloc((size_t)N * 64 * 4);
    float*  als1   = (float*) alloc((size_t)N * 4 * 4);
    float*  ald1   = (float*) alloc((size_t)N * 4 * 4);
    float*  als2   = (float*) alloc((size_t)N * 4);
    float*  ald2   = (float*) alloc((size_t)N * 4);

    hipMemsetAsync(cnt, 0, (size_t)N * 4, stream);
    const int ge = (E + 255) / 256;
    const int nb = (N + 1023) / 1024;
    k_hist<<<ge, 256, 0, stream>>>(ei + E, cnt, rank, E);
    k_scan1<<<nb, 1024, 0, stream>>>(cnt, cscan, bsum, N);
    k_scan2<<<1, 1024, 0, stream>>>(bsum, nb);
    k_scan3<<<nb, 1024, 0, stream>>>(cscan, bsum, rowptr, N);
    k_scatter<<<ge, 256, 0, stream>>>(ei, ei + E, rank, rowptr, csr, E);

    // fp16 conversions / weight packing
    const int n4x = N * 128 / 4;
    k_cvt16<<<(n4x + 255) / 256, 256, 0, stream>>>(x, xh, n4x);
    k_packW<<<(4096 + 255) / 256, 256, 0, stream>>>(W1, W1p, 128, 256);
    k_packW<<<(2048 + 255) / 256, 256, 0, stream>>>(W2, W2p, 256, 64);

    // Layer 1: MFMA GEMM [N,128]@[128,256] -> fp16 h1
    const int gw = (N / 16 + 3) / 4;
    k_gemm_mfma<128, 256><<<gw, 256, 0, stream>>>(xh, W1p, h1h, N);
    const int gn4 = (N + 3) / 4;
    k_al1<<<gn4, 256, 0, stream>>>(h1h, a_src1, a_dst1, als1, ald1, N);
    k_edge1<<<gn4, 256, 0, stream>>>(h1h, als1, ald1, rowptr, csr, b1, x2h, N);

    // Layer 2: MFMA GEMM [N,256]@[256,64] -> fp16 h2
    k_gemm_mfma<256, 64><<<gw, 256, 0, stream>>>(x2h, W2p, h2h, N);
    k_al2<<<gn4, 256, 0, stream>>>(h2h, a_src2, a_dst2, als2, ald2, N);
    k_edge2<<<gn4, 256, 0, stream>>>(h2h, als2, ald2, rowptr, csr, b2, out2, N);

    // Pool + FC
    k_pool<<<out_size, 1024, 0, stream>>>(out2, batch, fcW, fcb, out, N);
}

// Round 9
// 234.810 us; speedup vs baseline: 1.5785x; 1.0426x over previous
//
#include <hip/hip_runtime.h>
#include <hip/hip_fp16.h>
#include <cstddef>
#include <cstdint>

// N=50000, F_IN=128, HID=64, HEADS=4, E=800000, NG=64
// Layer1: x(fp32->fp16 in-reg)@W1p -> h1(fp16) via MFMA; GAT agg (scalar-idx 8-wide) -> x2 fp16
// Layer2: x2@W2p -> h2(fp16) via MFMA; GAT agg -> out2 fp32
// Pool: segment-mean by sorted batch -> [64,64]; fc -> [64]

#define LOG2E 1.4426950408889634f
__device__ __forceinline__ float lrelu02(float x) { return x >= 0.f ? x : 0.2f * x; }
__device__ __forceinline__ float elu1(float x)    { return x > 0.f ? x : expm1f(x); }
__device__ __forceinline__ float fexp(float x)    { return exp2f(x * LOG2E); }

typedef _Float16 f16x8 __attribute__((ext_vector_type(8)));
typedef float    f32x4 __attribute__((ext_vector_type(4)));

// ---------------- CSR build (by destination) ----------------
__global__ void k_hist(const int* __restrict__ dst, int* __restrict__ cnt,
                       int* __restrict__ rank, int e) {
    int i = blockIdx.x * 256 + threadIdx.x;
    if (i < e) rank[i] = atomicAdd(&cnt[dst[i]], 1);
}

__global__ __launch_bounds__(1024) void k_scan1(const int* __restrict__ cnt,
                                                int* __restrict__ cscan,
                                                int* __restrict__ bsum, int n) {
    __shared__ int ws[16];
    const int t = threadIdx.x, lane = t & 63, wv = t >> 6;
    const int i = blockIdx.x * 1024 + t;
    int v = (i < n) ? cnt[i] : 0;
    int s = v;
#pragma unroll
    for (int d = 1; d < 64; d <<= 1) { int o = __shfl_up(s, d); if (lane >= d) s += o; }
    if (lane == 63) ws[wv] = s;
    __syncthreads();
    if (t < 16) {
        int xx = ws[t];
#pragma unroll
        for (int d = 1; d < 16; d <<= 1) { int o = __shfl_up(xx, d); if (t >= d) xx += o; }
        ws[t] = xx;
        if (t == 15) bsum[blockIdx.x] = xx;
    }
    __syncthreads();
    int incl = s + (wv > 0 ? ws[wv - 1] : 0);
    if (i < n) cscan[i] = incl;
}

__global__ __launch_bounds__(1024) void k_scan2(int* __restrict__ bsum, int nb) {
    __shared__ int ws[16];
    const int t = threadIdx.x, lane = t & 63, wv = t >> 6;
    int v = (t < nb) ? bsum[t] : 0;
    int s = v;
#pragma unroll
    for (int d = 1; d < 64; d <<= 1) { int o = __shfl_up(s, d); if (lane >= d) s += o; }
    if (lane == 63) ws[wv] = s;
    __syncthreads();
    if (t < 16) {
        int xx = ws[t];
#pragma unroll
        for (int d = 1; d < 16; d <<= 1) { int o = __shfl_up(xx, d); if (t >= d) xx += o; }
        ws[t] = xx;
    }
    __syncthreads();
    int incl = s + (wv > 0 ? ws[wv - 1] : 0);
    if (t < nb) bsum[t] = incl - v;   // exclusive
}

__global__ __launch_bounds__(1024) void k_scan3(const int* __restrict__ cscan,
                                                const int* __restrict__ bsum,
                                                int* __restrict__ rowptr, int n) {
    const int i = blockIdx.x * 1024 + threadIdx.x;
    if (i < n) rowptr[i + 1] = cscan[i] + bsum[blockIdx.x];
    if (i == 0) rowptr[0] = 0;
}

__global__ void k_scatter(const int* __restrict__ src, const int* __restrict__ dstArr,
                          const int* __restrict__ rank, const int* __restrict__ rowptr,
                          int* __restrict__ csr, int e) {
    int i = blockIdx.x * 256 + threadIdx.x;
    if (i < e) csr[rowptr[dstArr[i]] + rank[i]] = src[i];
}

// ---------------- W pack: fp32 [K][N] row-major -> fragment-ordered fp16 ----------------
__global__ void k_packW(const float* __restrict__ W, __half* __restrict__ Bp, int K, int N) {
    int i = blockIdx.x * 256 + threadIdx.x;
    int total = (K / 32) * (N / 16) * 64;
    if (i >= total) return;
    int c = i & 15, q = (i >> 4) & 3, tnt = i >> 6;
    int nt = tnt % (N / 16), t = tnt / (N / 16);
    int k0 = t * 32 + q * 8, col = nt * 16 + c;
    __half tmp[8];
#pragma unroll
    for (int j = 0; j < 8; ++j) tmp[j] = __float2half(W[(size_t)(k0 + j) * N + col]);
    *reinterpret_cast<int4*>(Bp + (size_t)i * 8) = *reinterpret_cast<int4*>(tmp);
}

// ---------------- MFMA GEMM: C[M,N] = A[M,K] @ B[K,N], fp16 out ----------------
// AF32: A is fp32, converted in-register to fp16 (same rounding as a cvt pass).
template <int K, int N, bool AF32>
__global__ __launch_bounds__(256) void k_gemm_mfma(const void* __restrict__ Av,
                                                   const __half* __restrict__ Bp,
                                                   __half* __restrict__ C, int M) {
    constexpr int NT = N / 16, KT = K / 32;
    const int lane = threadIdx.x & 63;
    const int wv = threadIdx.x >> 6;
    const int row0 = (blockIdx.x * 4 + wv) * 16;
    if (row0 >= M) return;

    f32x4 acc[NT];
#pragma unroll
    for (int nt = 0; nt < NT; ++nt) acc[nt] = (f32x4){0.f, 0.f, 0.f, 0.f};

    const __half* Ah = (const __half*)Av;
    const float*  Af = (const float*)Av;
    const size_t arow = (size_t)(row0 + (lane & 15)) * K + (lane >> 4) * 8;
    const __half* Bb = Bp + (size_t)lane * 8;
#pragma unroll
    for (int t = 0; t < KT; ++t) {
        f16x8 a;
        if constexpr (AF32) {
            float4 u0 = *reinterpret_cast<const float4*>(Af + arow + t * 32);
            float4 u1 = *reinterpret_cast<const float4*>(Af + arow + t * 32 + 4);
            a[0] = (_Float16)u0.x; a[1] = (_Float16)u0.y;
            a[2] = (_Float16)u0.z; a[3] = (_Float16)u0.w;
            a[4] = (_Float16)u1.x; a[5] = (_Float16)u1.y;
            a[6] = (_Float16)u1.z; a[7] = (_Float16)u1.w;
        } else {
            a = *reinterpret_cast<const f16x8*>(Ah + arow + t * 32);
        }
#pragma unroll
        for (int nt = 0; nt < NT; ++nt) {
            f16x8 b = *reinterpret_cast<const f16x8*>(Bb + (size_t)(t * NT + nt) * 512);
            acc[nt] = __builtin_amdgcn_mfma_f32_16x16x32_f16(a, b, acc[nt], 0, 0, 0);
        }
    }
    const int r0 = row0 + (lane >> 4) * 4;
    const int cl = lane & 15;
#pragma unroll
    for (int nt = 0; nt < NT; ++nt) {
        int col = nt * 16 + cl;
#pragma unroll
        for (int j = 0; j < 4; ++j)
            C[(size_t)(r0 + j) * N + col] = __float2half(acc[nt][j]);
    }
}

__device__ __forceinline__ void load_h4(const __half* __restrict__ p, float2& lo, float2& hi) {
    float2 raw = *reinterpret_cast<const float2*>(p);   // 8B = 4 halves
    __half2* q = reinterpret_cast<__half2*>(&raw);
    lo = __half22float2(q[0]);
    hi = __half22float2(q[1]);
}

__device__ __forceinline__ void h4acc(float2 raw, float w, float& ax, float& ay,
                                      float& az, float& aw2) {
    __half2* q = reinterpret_cast<__half2*>(&raw);
    float2 lo = __half22float2(q[0]), hi = __half22float2(q[1]);
    ax = fmaf(w, lo.x, ax); ay = fmaf(w, lo.y, ay);
    az = fmaf(w, hi.x, az); aw2 = fmaf(w, hi.y, aw2);
}

// ---------------- attention logits, layer 1 ----------------
__global__ void k_al1(const __half* __restrict__ h1, const float* __restrict__ a_src,
                      const float* __restrict__ a_dst, float* __restrict__ als,
                      float* __restrict__ ald, int n) {
    const int lane = threadIdx.x & 63;
    const int node = (blockIdx.x << 2) + (threadIdx.x >> 6);
    if (node >= n) return;
    const int head = lane >> 4;
    float2 lo, hi;
    load_h4(h1 + (size_t)node * 256 + lane * 4, lo, hi);
    float4 av = *reinterpret_cast<const float4*>(a_src + lane * 4);
    float4 dv = *reinterpret_cast<const float4*>(a_dst + lane * 4);
    float ps = lo.x * av.x + lo.y * av.y + hi.x * av.z + hi.y * av.w;
    float pd = lo.x * dv.x + lo.y * dv.y + hi.x * dv.z + hi.y * dv.w;
#pragma unroll
    for (int d = 1; d < 16; d <<= 1) { ps += __shfl_xor(ps, d); pd += __shfl_xor(pd, d); }
    if ((lane & 15) == 0) { als[node * 4 + head] = ps; ald[node * 4 + head] = pd; }
}

// ---------------- edge aggregation, layer 1 ----------------
// 8 edges/iter. Edge indices loaded at WAVE-UNIFORM addresses (scalarized by the
// compiler) so the 8 row-gathers issue immediately; the weight chain (per-lane
// select + als gather + exp + shfl) overlaps with the gathers.
__global__ void k_edge1(const __half* __restrict__ h1, const float* __restrict__ als,
                        const float* __restrict__ ald, const int* __restrict__ rowptr,
                        const int* __restrict__ csr, const float* __restrict__ b1,
                        __half* __restrict__ x2, int n) {
    const int lane = threadIdx.x & 63;
    const int node = (blockIdx.x << 2) + (threadIdx.x >> 6);
    if (node >= n) return;
    const int head = lane >> 4;
    const int ch = lane * 4;
    const int e8 = lane & 7, h8 = (lane >> 3) & 3;
    const float adh  = ald[node * 4 + head];
    const float adh8 = ald[node * 4 + h8];
    const int wb = head << 3;
    float axA = 0.f, ayA = 0.f, azA = 0.f, awA = 0.f;
    float axB = 0.f, ayB = 0.f, azB = 0.f, awB = 0.f;
    float wsum = 0.f;
    const int beg = rowptr[node], end = rowptr[node + 1];
    int i = beg;
    for (; i + 8 <= end; i += 8) {
        // wave-uniform index loads -> scalar regs
        int s0 = csr[i + 0], s1 = csr[i + 1], s2 = csr[i + 2], s3 = csr[i + 3];
        int s4 = csr[i + 4], s5 = csr[i + 5], s6 = csr[i + 6], s7 = csr[i + 7];
        // row gathers issue now (addresses depend only on scalars)
        float2 r0 = *reinterpret_cast<const float2*>(h1 + (size_t)s0 * 256 + ch);
        float2 r1 = *reinterpret_cast<const float2*>(h1 + (size_t)s1 * 256 + ch);
        float2 r2 = *reinterpret_cast<const float2*>(h1 + (size_t)s2 * 256 + ch);
        float2 r3 = *reinterpret_cast<const float2*>(h1 + (size_t)s3 * 256 + ch);
        float2 r4 = *reinterpret_cast<const float2*>(h1 + (size_t)s4 * 256 + ch);
        float2 r5 = *reinterpret_cast<const float2*>(h1 + (size_t)s5 * 256 + ch);
        float2 r6 = *reinterpret_cast<const float2*>(h1 + (size_t)s6 * 256 + ch);
        float2 r7 = *reinterpret_cast<const float2*>(h1 + (size_t)s7 * 256 + ch);
        // weight chain (overlaps with gathers): lane -> (edge e8, head h8)
        int se = s0;
        se = (e8 == 1) ? s1 : se; se = (e8 == 2) ? s2 : se; se = (e8 == 3) ? s3 : se;
        se = (e8 == 4) ? s4 : se; se = (e8 == 5) ? s5 : se; se = (e8 == 6) ? s6 : se;
        se = (e8 == 7) ? s7 : se;
        float myw = fexp(lrelu02(als[(size_t)se * 4 + h8] + adh8));
        float w0 = __shfl(myw, wb + 0), w1 = __shfl(myw, wb + 1);
        float w2 = __shfl(myw, wb + 2), w3 = __shfl(myw, wb + 3);
        float w4 = __shfl(myw, wb + 4), w5 = __shfl(myw, wb + 5);
        float w6 = __shfl(myw, wb + 6), w7 = __shfl(myw, wb + 7);
        h4acc(r0, w0, axA, ayA, azA, awA);
        h4acc(r1, w1, axB, ayB, azB, awB);
        h4acc(r2, w2, axA, ayA, azA, awA);
        h4acc(r3, w3, axB, ayB, azB, awB);
        h4acc(r4, w4, axA, ayA, azA, awA);
        h4acc(r5, w5, axB, ayB, azB, awB);
        h4acc(r6, w6, axA, ayA, azA, awA);
        h4acc(r7, w7, axB, ayB, azB, awB);
        wsum += ((w0 + w1) + (w2 + w3)) + ((w4 + w5) + (w6 + w7));
    }
    float ax = axA + axB, ay = ayA + ayB, az = azA + azB, aw = awA + awB;
    for (; i < end; ++i) {
        int s0 = csr[i];
        float w0 = fexp(lrelu02(als[(size_t)s0 * 4 + head] + adh));
        float2 l0, u0;
        load_h4(h1 + (size_t)s0 * 256 + ch, l0, u0);
        ax += w0 * l0.x; ay += w0 * l0.y; az += w0 * u0.x; aw += w0 * u0.y;
        wsum += w0;
    }
    {   // self loop
        float w0 = fexp(lrelu02(als[node * 4 + head] + adh));
        float2 l0, u0;
        load_h4(h1 + (size_t)node * 256 + ch, l0, u0);
        ax += w0 * l0.x; ay += w0 * l0.y; az += w0 * u0.x; aw += w0 * u0.y;
        wsum += w0;
    }
    const float inv = 1.f / (wsum + 1e-16f);
    float4 bv = *reinterpret_cast<const float4*>(b1 + ch);
    __half2 r0 = __floats2half2_rn(elu1(ax * inv + bv.x), elu1(ay * inv + bv.y));
    __half2 r1 = __floats2half2_rn(elu1(az * inv + bv.z), elu1(aw * inv + bv.w));
    int2 p;
    p.x = *reinterpret_cast<int*>(&r0);
    p.y = *reinterpret_cast<int*>(&r1);
    *reinterpret_cast<int2*>(x2 + (size_t)node * 256 + ch) = p;
}

// ---------------- attention logits, layer 2 ----------------
__global__ void k_al2(const __half* __restrict__ h2, const float* __restrict__ a_src,
                      const float* __restrict__ a_dst, float* __restrict__ als,
                      float* __restrict__ ald, int n) {
    const int lane = threadIdx.x & 63;
    const int node = (blockIdx.x << 2) + (threadIdx.x >> 6);
    if (node >= n) return;
    float hv = __half2float(h2[(size_t)node * 64 + lane]);
    float ps = hv * a_src[lane];
    float pd = hv * a_dst[lane];
#pragma unroll
    for (int d = 1; d < 64; d <<= 1) { ps += __shfl_xor(ps, d); pd += __shfl_xor(pd, d); }
    if (lane == 0) { als[node] = ps; ald[node] = pd; }
}

// ---------------- edge aggregation, layer 2 (scalar-idx 8-wide) ----------------
__global__ void k_edge2(const __half* __restrict__ h2, const float* __restrict__ als,
                        const float* __restrict__ ald, const int* __restrict__ rowptr,
                        const int* __restrict__ csr, const float* __restrict__ b2,
                        float* __restrict__ out2, int n) {
    const int lane = threadIdx.x & 63;
    const int node = (blockIdx.x << 2) + (threadIdx.x >> 6);
    if (node >= n) return;
    const int e8 = lane & 7;
    const float adl = ald[node];
    float accA = 0.f, accB = 0.f, wsum = 0.f;
    const int beg = rowptr[node], end = rowptr[node + 1];
    int i = beg;
    for (; i + 8 <= end; i += 8) {
        int s0 = csr[i + 0], s1 = csr[i + 1], s2 = csr[i + 2], s3 = csr[i + 3];
        int s4 = csr[i + 4], s5 = csr[i + 5], s6 = csr[i + 6], s7 = csr[i + 7];
        float v0 = __half2float(h2[(size_t)s0 * 64 + lane]);
        float v1 = __half2float(h2[(size_t)s1 * 64 + lane]);
        float v2 = __half2float(h2[(size_t)s2 * 64 + lane]);
        float v3 = __half2float(h2[(size_t)s3 * 64 + lane]);
        float v4 = __half2float(h2[(size_t)s4 * 64 + lane]);
        float v5 = __half2float(h2[(size_t)s5 * 64 + lane]);
        float v6 = __half2float(h2[(size_t)s6 * 64 + lane]);
        float v7 = __half2float(h2[(size_t)s7 * 64 + lane]);
        int se = s0;
        se = (e8 == 1) ? s1 : se; se = (e8 == 2) ? s2 : se; se = (e8 == 3) ? s3 : se;
        se = (e8 == 4) ? s4 : se; se = (e8 == 5) ? s5 : se; se = (e8 == 6) ? s6 : se;
        se = (e8 == 7) ? s7 : se;
        float myw = fexp(lrelu02(als[se] + adl));
        float w0 = __shfl(myw, 0), w1 = __shfl(myw, 1), w2 = __shfl(myw, 2), w3 = __shfl(myw, 3);
        float w4 = __shfl(myw, 4), w5 = __shfl(myw, 5), w6 = __shfl(myw, 6), w7 = __shfl(myw, 7);
        accA = fmaf(w0, v0, accA); accB = fmaf(w1, v1, accB);
        accA = fmaf(w2, v2, accA); accB = fmaf(w3, v3, accB);
        accA = fmaf(w4, v4, accA); accB = fmaf(w5, v5, accB);
        accA = fmaf(w6, v6, accA); accB = fmaf(w7, v7, accB);
        wsum += (w0 + w1 + w2 + w3) + (w4 + w5 + w6 + w7);
    }
    float acc = accA + accB;
    for (; i < end; ++i) {
        int s0 = csr[i];
        float w0 = fexp(lrelu02(als[s0] + adl));
        acc += w0 * __half2float(h2[(size_t)s0 * 64 + lane]);
        wsum += w0;
    }
    {   // self loop
        float w0 = fexp(lrelu02(als[node] + adl));
        acc += w0 * __half2float(h2[(size_t)node * 64 + lane]);
        wsum += w0;
    }
    float o = acc / (wsum + 1e-16f) + b2[lane];
    out2[(size_t)node * 64 + lane] = elu1(o);
}

// ---------------- pool (mean by sorted batch) + fc ----------------
__global__ __launch_bounds__(1024) void k_pool(const float* __restrict__ out2,
                                               const int* __restrict__ batch,
                                               const float* __restrict__ fcW,
                                               const float* __restrict__ fcb,
                                               float* __restrict__ out, int n) {
    __shared__ float sbuf[16][64];
    const int g = blockIdx.x;
    const int lane = threadIdx.x & 63, wv = threadIdx.x >> 6;
    int lo0 = 0, hi0 = n;
    while (lo0 < hi0) { int mid = (lo0 + hi0) >> 1; if (batch[mid] < g) lo0 = mid + 1; else hi0 = mid; }
    int lo1 = lo0, hi1 = n;
    while (lo1 < hi1) { int mid = (lo1 + hi1) >> 1; if (batch[mid] < g + 1) lo1 = mid + 1; else hi1 = mid; }
    float s0 = 0.f, s1 = 0.f;
    int r = lo0 + wv;
    for (; r + 16 < lo1; r += 32) {
        s0 += out2[(size_t)r * 64 + lane];
        s1 += out2[(size_t)(r + 16) * 64 + lane];
    }
    if (r < lo1) s0 += out2[(size_t)r * 64 + lane];
    sbuf[wv][lane] = s0 + s1;
    __syncthreads();
    if (wv == 0) {
        float s = 0.f;
#pragma unroll
        for (int k = 0; k < 16; ++k) s += sbuf[k][lane];
        float cntf = (float)(lo1 - lo0);
        float pooled = s / fmaxf(cntf, 1.f);
        float v = pooled * fcW[lane];
#pragma unroll
        for (int d = 32; d; d >>= 1) v += __shfl_xor(v, d);
        if (lane == 0) out[g] = v + fcb[0];
    }
}

// ---------------- host launcher ----------------
extern "C" void kernel_launch(void* const* d_in, const int* in_sizes, int n_in,
                              void* d_out, int out_size, void* d_ws, size_t ws_size,
                              hipStream_t stream) {
    const float* x      = (const float*)d_in[0];
    const int*   ei     = (const int*)  d_in[1];
    const int*   batch  = (const int*)  d_in[2];
    const float* W1     = (const float*)d_in[3];
    const float* a_src1 = (const float*)d_in[4];
    const float* a_dst1 = (const float*)d_in[5];
    const float* b1     = (const float*)d_in[6];
    const float* W2     = (const float*)d_in[7];
    const float* a_src2 = (const float*)d_in[8];
    const float* a_dst2 = (const float*)d_in[9];
    const float* b2     = (const float*)d_in[10];
    const float* fcW    = (const float*)d_in[11];
    const float* fcb    = (const float*)d_in[12];
    float* out = (float*)d_out;

    const int N = in_sizes[2];
    const int E = in_sizes[1] / 2;
    (void)n_in; (void)ws_size;

    char* ws = (char*)d_ws;
    size_t off = 0;
    auto alloc = [&](size_t bytes) -> char* {
        char* p = ws + off;
        off += (bytes + 255) & ~(size_t)255;
        return p;
    };
    int*    cnt    = (int*)   alloc((size_t)N * 4);
    int*    cscan  = (int*)   alloc((size_t)N * 4);
    int*    bsum   = (int*)   alloc((size_t)1024 * 4);
    int*    rank   = (int*)   alloc((size_t)E * 4);
    int*    rowptr = (int*)   alloc((size_t)(N + 1) * 4);
    int*    csr    = (int*)   alloc((size_t)E * 4);
    __half* W1p    = (__half*)alloc((size_t)128 * 256 * 2);
    __half* W2p    = (__half*)alloc((size_t)256 * 64 * 2);
    __half* h1h    = (__half*)alloc((size_t)N * 256 * 2);
    __half* x2h    = (__half*)alloc((size_t)N * 256 * 2);
    __half* h2h    = (__half*)alloc((size_t)N * 64 * 2);
    float*  out2   = (float*) alloc((size_t)N * 64 * 4);
    float*  als1   = (float*) alloc((size_t)N * 4 * 4);
    float*  ald1   = (float*) alloc((size_t)N * 4 * 4);
    float*  als2   = (float*) alloc((size_t)N * 4);
    float*  ald2   = (float*) alloc((size_t)N * 4);

    hipMemsetAsync(cnt, 0, (size_t)N * 4, stream);
    const int ge = (E + 255) / 256;
    const int nb = (N + 1023) / 1024;
    k_hist<<<ge, 256, 0, stream>>>(ei + E, cnt, rank, E);
    k_scan1<<<nb, 1024, 0, stream>>>(cnt, cscan, bsum, N);
    k_scan2<<<1, 1024, 0, stream>>>(bsum, nb);
    k_scan3<<<nb, 1024, 0, stream>>>(cscan, bsum, rowptr, N);
    k_scatter<<<ge, 256, 0, stream>>>(ei, ei + E, rank, rowptr, csr, E);

    // weight packing
    k_packW<<<(4096 + 255) / 256, 256, 0, stream>>>(W1, W1p, 128, 256);
    k_packW<<<(2048 + 255) / 256, 256, 0, stream>>>(W2, W2p, 256, 64);

    // Layer 1: MFMA GEMM [N,128](fp32 A, in-reg cvt)@[128,256] -> fp16 h1
    const int gw = (N / 16 + 3) / 4;
    k_gemm_mfma<128, 256, true><<<gw, 256, 0, stream>>>(x, W1p, h1h, N);
    const int gn4 = (N + 3) / 4;
    k_al1<<<gn4, 256, 0, stream>>>(h1h, a_src1, a_dst1, als1, ald1, N);
    k_edge1<<<gn4, 256, 0, stream>>>(h1h, als1, ald1, rowptr, csr, b1, x2h, N);

    // Layer 2: MFMA GEMM [N,256]@[256,64] -> fp16 h2
    k_gemm_mfma<256, 64, false><<<gw, 256, 0, stream>>>(x2h, W2p, h2h, N);
    k_al2<<<gn4, 256, 0, stream>>>(h2h, a_src2, a_dst2, als2, ald2, N);
    k_edge2<<<gn4, 256, 0, stream>>>(h2h, als2, ald2, rowptr, csr, b2, out2, N);

    // Pool + FC
    k_pool<<<out_size, 1024, 0, stream>>>(out2, batch, fcW, fcb, out, N);
}

// Round 10
// 218.156 us; speedup vs baseline: 1.6990x; 1.0763x over previous
//
#include <hip/hip_runtime.h>
#include <hip/hip_fp16.h>
#include <cstddef>
#include <cstdint>

// N=50000, F_IN=128, HID=64, HEADS=4, E=800000, NG=64
// Layer1: x(fp32->fp16 in-reg)@W1p -> h1(fp16) + fused als1/ald1 via MFMA epilogue;
//         GAT agg (masked 8-wide, virtual self-loop) -> x2 fp16
// Layer2: x2@W2p -> h2(fp16) + fused als2/ald2; GAT agg -> out2 fp32
// Pool: segment-mean by sorted batch -> [64,64]; fc -> [64]

#define LOG2E 1.4426950408889634f
__device__ __forceinline__ float lrelu02(float x) { return x >= 0.f ? x : 0.2f * x; }
__device__ __forceinline__ float elu1(float x)    { return x > 0.f ? x : expm1f(x); }
__device__ __forceinline__ float fexp(float x)    { return exp2f(x * LOG2E); }

typedef _Float16 f16x8 __attribute__((ext_vector_type(8)));
typedef float    f32x4 __attribute__((ext_vector_type(4)));

// ---------------- CSR build (by destination) ----------------
__global__ void k_hist(const int* __restrict__ dst, int* __restrict__ cnt,
                       int* __restrict__ rank, int e) {
    int i = blockIdx.x * 256 + threadIdx.x;
    if (i < e) rank[i] = atomicAdd(&cnt[dst[i]], 1);
}

__global__ __launch_bounds__(1024) void k_scan1(const int* __restrict__ cnt,
                                                int* __restrict__ cscan,
                                                int* __restrict__ bsum, int n) {
    __shared__ int ws[16];
    const int t = threadIdx.x, lane = t & 63, wv = t >> 6;
    const int i = blockIdx.x * 1024 + t;
    int v = (i < n) ? cnt[i] : 0;
    int s = v;
#pragma unroll
    for (int d = 1; d < 64; d <<= 1) { int o = __shfl_up(s, d); if (lane >= d) s += o; }
    if (lane == 63) ws[wv] = s;
    __syncthreads();
    if (t < 16) {
        int xx = ws[t];
#pragma unroll
        for (int d = 1; d < 16; d <<= 1) { int o = __shfl_up(xx, d); if (t >= d) xx += o; }
        ws[t] = xx;
        if (t == 15) bsum[blockIdx.x] = xx;
    }
    __syncthreads();
    int incl = s + (wv > 0 ? ws[wv - 1] : 0);
    if (i < n) cscan[i] = incl;
}

__global__ __launch_bounds__(1024) void k_scan2(int* __restrict__ bsum, int nb) {
    __shared__ int ws[16];
    const int t = threadIdx.x, lane = t & 63, wv = t >> 6;
    int v = (t < nb) ? bsum[t] : 0;
    int s = v;
#pragma unroll
    for (int d = 1; d < 64; d <<= 1) { int o = __shfl_up(s, d); if (lane >= d) s += o; }
    if (lane == 63) ws[wv] = s;
    __syncthreads();
    if (t < 16) {
        int xx = ws[t];
#pragma unroll
        for (int d = 1; d < 16; d <<= 1) { int o = __shfl_up(xx, d); if (t >= d) xx += o; }
        ws[t] = xx;
    }
    __syncthreads();
    int incl = s + (wv > 0 ? ws[wv - 1] : 0);
    if (t < nb) bsum[t] = incl - v;   // exclusive
}

__global__ __launch_bounds__(1024) void k_scan3(const int* __restrict__ cscan,
                                                const int* __restrict__ bsum,
                                                int* __restrict__ rowptr, int n) {
    const int i = blockIdx.x * 1024 + threadIdx.x;
    if (i < n) rowptr[i + 1] = cscan[i] + bsum[blockIdx.x];
    if (i == 0) rowptr[0] = 0;
}

__global__ void k_scatter(const int* __restrict__ src, const int* __restrict__ dstArr,
                          const int* __restrict__ rank, const int* __restrict__ rowptr,
                          int* __restrict__ csr, int e) {
    int i = blockIdx.x * 256 + threadIdx.x;
    if (i < e) csr[rowptr[dstArr[i]] + rank[i]] = src[i];
}

// ---------------- W pack (both weights in one launch) ----------------
__device__ __forceinline__ void packOne(const float* __restrict__ W, __half* __restrict__ Bp,
                                        int K, int N, int i) {
    int c = i & 15, q = (i >> 4) & 3, tnt = i >> 6;
    int nt = tnt % (N / 16), t = tnt / (N / 16);
    int k0 = t * 32 + q * 8, col = nt * 16 + c;
    __half tmp[8];
#pragma unroll
    for (int j = 0; j < 8; ++j) tmp[j] = __float2half(W[(size_t)(k0 + j) * N + col]);
    *reinterpret_cast<int4*>(Bp + (size_t)i * 8) = *reinterpret_cast<int4*>(tmp);
}

__global__ void k_packW(const float* __restrict__ W1, __half* __restrict__ B1,
                        const float* __restrict__ W2, __half* __restrict__ B2) {
    int i = blockIdx.x * 256 + threadIdx.x;
    if (i < 4096) packOne(W1, B1, 128, 256, i);
    else if (i < 4096 + 2048) packOne(W2, B2, 256, 64, i - 4096);
}

// ---------------- MFMA GEMM + fused attention logits ----------------
// C[M,N] = A[M,K] @ B[K,N] (fp16 out). AF32: A fp32, in-reg cvt to fp16.
// Epilogue also computes als/ald: per row r, head h: sum_c acc_row[c]*a_{src,dst}[h][c],
// reduced over the 16 lanes holding the row (shfl_xor within 16-lane group).
template <int K, int N, bool AF32, int HEADS_>
__global__ __launch_bounds__(256) void k_gemm_mfma(const void* __restrict__ Av,
                                                   const __half* __restrict__ Bp,
                                                   __half* __restrict__ C,
                                                   const float* __restrict__ a_src,
                                                   const float* __restrict__ a_dst,
                                                   float* __restrict__ als,
                                                   float* __restrict__ ald, int M) {
    constexpr int NT = N / 16, KT = K / 32;
    const int lane = threadIdx.x & 63;
    const int wv = threadIdx.x >> 6;
    const int row0 = (blockIdx.x * 4 + wv) * 16;
    if (row0 >= M) return;

    f32x4 acc[NT];
#pragma unroll
    for (int nt = 0; nt < NT; ++nt) acc[nt] = (f32x4){0.f, 0.f, 0.f, 0.f};

    const __half* Ah = (const __half*)Av;
    const float*  Af = (const float*)Av;
    const size_t arow = (size_t)(row0 + (lane & 15)) * K + (lane >> 4) * 8;
    const __half* Bb = Bp + (size_t)lane * 8;
#pragma unroll
    for (int t = 0; t < KT; ++t) {
        f16x8 a;
        if constexpr (AF32) {
            float4 u0 = *reinterpret_cast<const float4*>(Af + arow + t * 32);
            float4 u1 = *reinterpret_cast<const float4*>(Af + arow + t * 32 + 4);
            a[0] = (_Float16)u0.x; a[1] = (_Float16)u0.y;
            a[2] = (_Float16)u0.z; a[3] = (_Float16)u0.w;
            a[4] = (_Float16)u1.x; a[5] = (_Float16)u1.y;
            a[6] = (_Float16)u1.z; a[7] = (_Float16)u1.w;
        } else {
            a = *reinterpret_cast<const f16x8*>(Ah + arow + t * 32);
        }
#pragma unroll
        for (int nt = 0; nt < NT; ++nt) {
            f16x8 b = *reinterpret_cast<const f16x8*>(Bb + (size_t)(t * NT + nt) * 512);
            acc[nt] = __builtin_amdgcn_mfma_f32_16x16x32_f16(a, b, acc[nt], 0, 0, 0);
        }
    }
    const int r0 = row0 + (lane >> 4) * 4;
    const int cl = lane & 15;
#pragma unroll
    for (int nt = 0; nt < NT; ++nt) {
        int col = nt * 16 + cl;
#pragma unroll
        for (int j = 0; j < 4; ++j)
            C[(size_t)(r0 + j) * N + col] = __float2half(acc[nt][j]);
    }
    // fused attention logits
    float av[NT], dv[NT];
#pragma unroll
    for (int nt = 0; nt < NT; ++nt) {
        av[nt] = a_src[nt * 16 + cl];
        dv[nt] = a_dst[nt * 16 + cl];
    }
    constexpr int NTH = NT / HEADS_;
#pragma unroll
    for (int j = 0; j < 4; ++j) {
#pragma unroll
        for (int h = 0; h < HEADS_; ++h) {
            float ps = 0.f, pd = 0.f;
#pragma unroll
            for (int t = 0; t < NTH; ++t) {
                ps = fmaf(acc[h * NTH + t][j], av[h * NTH + t], ps);
                pd = fmaf(acc[h * NTH + t][j], dv[h * NTH + t], pd);
            }
#pragma unroll
            for (int d = 1; d < 16; d <<= 1) { ps += __shfl_xor(ps, d); pd += __shfl_xor(pd, d); }
            if (cl == 0) {
                int r = r0 + j;
                als[(size_t)r * HEADS_ + h] = ps;
                ald[(size_t)r * HEADS_ + h] = pd;
            }
        }
    }
}

__device__ __forceinline__ void h4acc(float2 raw, float w, float& ax, float& ay,
                                      float& az, float& aw2) {
    __half2* q = reinterpret_cast<__half2*>(&raw);
    float2 lo = __half22float2(q[0]), hi = __half22float2(q[1]);
    ax = fmaf(w, lo.x, ax); ay = fmaf(w, lo.y, ay);
    az = fmaf(w, hi.x, az); aw2 = fmaf(w, hi.y, aw2);
}

// ---------------- edge aggregation, layer 1 ----------------
// Row processed as deg+1 slots (last = self-loop), all in the masked 8-wide path.
// Edge indices loaded at wave-uniform addresses (scalarized); weight chain
// (per-lane select + als gather + exp + shfl) overlaps the 8 row-gathers.
__global__ void k_edge1(const __half* __restrict__ h1, const float* __restrict__ als,
                        const float* __restrict__ ald, const int* __restrict__ rowptr,
                        const int* __restrict__ csr, const float* __restrict__ b1,
                        __half* __restrict__ x2, int n) {
    const int lane = threadIdx.x & 63;
    const int node = (blockIdx.x << 2) + (threadIdx.x >> 6);
    if (node >= n) return;
    const int ch = lane * 4;
    const int e8 = lane & 7, h8 = (lane >> 3) & 3;
    const float adh8 = ald[node * 4 + h8];
    const int head = lane >> 4;
    const int wb = head << 3;
    float axA = 0.f, ayA = 0.f, azA = 0.f, awA = 0.f;
    float axB = 0.f, ayB = 0.f, azB = 0.f, awB = 0.f;
    float wsum = 0.f;
    const int beg = rowptr[node];
    const int deg = rowptr[node + 1] - beg;
    for (int base = 0; base <= deg; base += 8) {
        // wave-uniform index loads (csr has +8 slack) -> scalar regs; slot deg = self
        int s0 = (base + 0 < deg) ? csr[beg + base + 0] : node;
        int s1 = (base + 1 < deg) ? csr[beg + base + 1] : node;
        int s2 = (base + 2 < deg) ? csr[beg + base + 2] : node;
        int s3 = (base + 3 < deg) ? csr[beg + base + 3] : node;
        int s4 = (base + 4 < deg) ? csr[beg + base + 4] : node;
        int s5 = (base + 5 < deg) ? csr[beg + base + 5] : node;
        int s6 = (base + 6 < deg) ? csr[beg + base + 6] : node;
        int s7 = (base + 7 < deg) ? csr[beg + base + 7] : node;
        float2 r0 = *reinterpret_cast<const float2*>(h1 + (size_t)s0 * 256 + ch);
        float2 r1 = *reinterpret_cast<const float2*>(h1 + (size_t)s1 * 256 + ch);
        float2 r2 = *reinterpret_cast<const float2*>(h1 + (size_t)s2 * 256 + ch);
        float2 r3 = *reinterpret_cast<const float2*>(h1 + (size_t)s3 * 256 + ch);
        float2 r4 = *reinterpret_cast<const float2*>(h1 + (size_t)s4 * 256 + ch);
        float2 r5 = *reinterpret_cast<const float2*>(h1 + (size_t)s5 * 256 + ch);
        float2 r6 = *reinterpret_cast<const float2*>(h1 + (size_t)s6 * 256 + ch);
        float2 r7 = *reinterpret_cast<const float2*>(h1 + (size_t)s7 * 256 + ch);
        int se = s0;
        se = (e8 == 1) ? s1 : se; se = (e8 == 2) ? s2 : se; se = (e8 == 3) ? s3 : se;
        se = (e8 == 4) ? s4 : se; se = (e8 == 5) ? s5 : se; se = (e8 == 6) ? s6 : se;
        se = (e8 == 7) ? s7 : se;
        float myw = (base + e8 <= deg)
                        ? fexp(lrelu02(als[(size_t)se * 4 + h8] + adh8)) : 0.f;
        float w0 = __shfl(myw, wb + 0), w1 = __shfl(myw, wb + 1);
        float w2 = __shfl(myw, wb + 2), w3 = __shfl(myw, wb + 3);
        float w4 = __shfl(myw, wb + 4), w5 = __shfl(myw, wb + 5);
        float w6 = __shfl(myw, wb + 6), w7 = __shfl(myw, wb + 7);
        h4acc(r0, w0, axA, ayA, azA, awA);
        h4acc(r1, w1, axB, ayB, azB, awB);
        h4acc(r2, w2, axA, ayA, azA, awA);
        h4acc(r3, w3, axB, ayB, azB, awB);
        h4acc(r4, w4, axA, ayA, azA, awA);
        h4acc(r5, w5, axB, ayB, azB, awB);
        h4acc(r6, w6, axA, ayA, azA, awA);
        h4acc(r7, w7, axB, ayB, azB, awB);
        wsum += ((w0 + w1) + (w2 + w3)) + ((w4 + w5) + (w6 + w7));
    }
    float ax = axA + axB, ay = ayA + ayB, az = azA + azB, aw = awA + awB;
    const float inv = 1.f / (wsum + 1e-16f);
    float4 bv = *reinterpret_cast<const float4*>(b1 + ch);
    __half2 o0 = __floats2half2_rn(elu1(ax * inv + bv.x), elu1(ay * inv + bv.y));
    __half2 o1 = __floats2half2_rn(elu1(az * inv + bv.z), elu1(aw * inv + bv.w));
    int2 p;
    p.x = *reinterpret_cast<int*>(&o0);
    p.y = *reinterpret_cast<int*>(&o1);
    *reinterpret_cast<int2*>(x2 + (size_t)node * 256 + ch) = p;
}

// ---------------- edge aggregation, layer 2 (masked 8-wide) ----------------
__global__ void k_edge2(const __half* __restrict__ h2, const float* __restrict__ als,
                        const float* __restrict__ ald, const int* __restrict__ rowptr,
                        const int* __restrict__ csr, const float* __restrict__ b2,
                        float* __restrict__ out2, int n) {
    const int lane = threadIdx.x & 63;
    const int node = (blockIdx.x << 2) + (threadIdx.x >> 6);
    if (node >= n) return;
    const int e8 = lane & 7;
    const float adl = ald[node];
    float accA = 0.f, accB = 0.f, wsum = 0.f;
    const int beg = rowptr[node];
    const int deg = rowptr[node + 1] - beg;
    for (int base = 0; base <= deg; base += 8) {
        int s0 = (base + 0 < deg) ? csr[beg + base + 0] : node;
        int s1 = (base + 1 < deg) ? csr[beg + base + 1] : node;
        int s2 = (base + 2 < deg) ? csr[beg + base + 2] : node;
        int s3 = (base + 3 < deg) ? csr[beg + base + 3] : node;
        int s4 = (base + 4 < deg) ? csr[beg + base + 4] : node;
        int s5 = (base + 5 < deg) ? csr[beg + base + 5] : node;
        int s6 = (base + 6 < deg) ? csr[beg + base + 6] : node;
        int s7 = (base + 7 < deg) ? csr[beg + base + 7] : node;
        float v0 = __half2float(h2[(size_t)s0 * 64 + lane]);
        float v1 = __half2float(h2[(size_t)s1 * 64 + lane]);
        float v2 = __half2float(h2[(size_t)s2 * 64 + lane]);
        float v3 = __half2float(h2[(size_t)s3 * 64 + lane]);
        float v4 = __half2float(h2[(size_t)s4 * 64 + lane]);
        float v5 = __half2float(h2[(size_t)s5 * 64 + lane]);
        float v6 = __half2float(h2[(size_t)s6 * 64 + lane]);
        float v7 = __half2float(h2[(size_t)s7 * 64 + lane]);
        int se = s0;
        se = (e8 == 1) ? s1 : se; se = (e8 == 2) ? s2 : se; se = (e8 == 3) ? s3 : se;
        se = (e8 == 4) ? s4 : se; se = (e8 == 5) ? s5 : se; se = (e8 == 6) ? s6 : se;
        se = (e8 == 7) ? s7 : se;
        float myw = (base + e8 <= deg) ? fexp(lrelu02(als[se] + adl)) : 0.f;
        float w0 = __shfl(myw, 0), w1 = __shfl(myw, 1), w2 = __shfl(myw, 2), w3 = __shfl(myw, 3);
        float w4 = __shfl(myw, 4), w5 = __shfl(myw, 5), w6 = __shfl(myw, 6), w7 = __shfl(myw, 7);
        accA = fmaf(w0, v0, accA); accB = fmaf(w1, v1, accB);
        accA = fmaf(w2, v2, accA); accB = fmaf(w3, v3, accB);
        accA = fmaf(w4, v4, accA); accB = fmaf(w5, v5, accB);
        accA = fmaf(w6, v6, accA); accB = fmaf(w7, v7, accB);
        wsum += (w0 + w1 + w2 + w3) + (w4 + w5 + w6 + w7);
    }
    float acc = accA + accB;
    float o = acc / (wsum + 1e-16f) + b2[lane];
    out2[(size_t)node * 64 + lane] = elu1(o);
}

// ---------------- pool (mean by sorted batch) + fc ----------------
__global__ __launch_bounds__(1024) void k_pool(const float* __restrict__ out2,
                                               const int* __restrict__ batch,
                                               const float* __restrict__ fcW,
                                               const float* __restrict__ fcb,
                                               float* __restrict__ out, int n) {
    __shared__ float sbuf[16][64];
    const int g = blockIdx.x;
    const int lane = threadIdx.x & 63, wv = threadIdx.x >> 6;
    int lo0 = 0, hi0 = n;
    while (lo0 < hi0) { int mid = (lo0 + hi0) >> 1; if (batch[mid] < g) lo0 = mid + 1; else hi0 = mid; }
    int lo1 = lo0, hi1 = n;
    while (lo1 < hi1) { int mid = (lo1 + hi1) >> 1; if (batch[mid] < g + 1) lo1 = mid + 1; else hi1 = mid; }
    float s0 = 0.f, s1 = 0.f;
    int r = lo0 + wv;
    for (; r + 16 < lo1; r += 32) {
        s0 += out2[(size_t)r * 64 + lane];
        s1 += out2[(size_t)(r + 16) * 64 + lane];
    }
    if (r < lo1) s0 += out2[(size_t)r * 64 + lane];
    sbuf[wv][lane] = s0 + s1;
    __syncthreads();
    if (wv == 0) {
        float s = 0.f;
#pragma unroll
        for (int k = 0; k < 16; ++k) s += sbuf[k][lane];
        float cntf = (float)(lo1 - lo0);
        float pooled = s / fmaxf(cntf, 1.f);
        float v = pooled * fcW[lane];
#pragma unroll
        for (int d = 32; d; d >>= 1) v += __shfl_xor(v, d);
        if (lane == 0) out[g] = v + fcb[0];
    }
}

// ---------------- host launcher ----------------
extern "C" void kernel_launch(void* const* d_in, const int* in_sizes, int n_in,
                              void* d_out, int out_size, void* d_ws, size_t ws_size,
                              hipStream_t stream) {
    const float* x      = (const float*)d_in[0];
    const int*   ei     = (const int*)  d_in[1];
    const int*   batch  = (const int*)  d_in[2];
    const float* W1     = (const float*)d_in[3];
    const float* a_src1 = (const float*)d_in[4];
    const float* a_dst1 = (const float*)d_in[5];
    const float* b1     = (const float*)d_in[6];
    const float* W2     = (const float*)d_in[7];
    const float* a_src2 = (const float*)d_in[8];
    const float* a_dst2 = (const float*)d_in[9];
    const float* b2     = (const float*)d_in[10];
    const float* fcW    = (const float*)d_in[11];
    const float* fcb    = (const float*)d_in[12];
    float* out = (float*)d_out;

    const int N = in_sizes[2];
    const int E = in_sizes[1] / 2;
    (void)n_in; (void)ws_size;

    char* ws = (char*)d_ws;
    size_t off = 0;
    auto alloc = [&](size_t bytes) -> char* {
        char* p = ws + off;
        off += (bytes + 255) & ~(size_t)255;
        return p;
    };
    int*    cnt    = (int*)   alloc((size_t)N * 4);
    int*    cscan  = (int*)   alloc((size_t)N * 4);
    int*    bsum   = (int*)   alloc((size_t)1024 * 4);
    int*    rank   = (int*)   alloc((size_t)E * 4);
    int*    rowptr = (int*)   alloc((size_t)(N + 1) * 4);
    int*    csr    = (int*)   alloc((size_t)(E + 8) * 4);
    __half* W1p    = (__half*)alloc((size_t)128 * 256 * 2);
    __half* W2p    = (__half*)alloc((size_t)256 * 64 * 2);
    __half* h1h    = (__half*)alloc((size_t)N * 256 * 2);
    __half* x2h    = (__half*)alloc((size_t)N * 256 * 2);
    __half* h2h    = (__half*)alloc((size_t)N * 64 * 2);
    float*  out2   = (float*) alloc((size_t)N * 64 * 4);
    float*  als1   = (float*) alloc((size_t)N * 4 * 4);
    float*  ald1   = (float*) alloc((size_t)N * 4 * 4);
    float*  als2   = (float*) alloc((size_t)N * 4);
    float*  ald2   = (float*) alloc((size_t)N * 4);

    hipMemsetAsync(cnt, 0, (size_t)N * 4, stream);
    const int ge = (E + 255) / 256;
    const int nb = (N + 1023) / 1024;
    k_hist<<<ge, 256, 0, stream>>>(ei + E, cnt, rank, E);
    k_scan1<<<nb, 1024, 0, stream>>>(cnt, cscan, bsum, N);
    k_scan2<<<1, 1024, 0, stream>>>(bsum, nb);
    k_scan3<<<nb, 1024, 0, stream>>>(cscan, bsum, rowptr, N);
    k_scatter<<<ge, 256, 0, stream>>>(ei, ei + E, rank, rowptr, csr, E);

    // weight packing (both layers, one launch)
    k_packW<<<24, 256, 0, stream>>>(W1, W1p, W2, W2p);

    // Layer 1: MFMA GEMM [N,128](fp32 A)@[128,256] -> fp16 h1 + fused als1/ald1
    const int gw = (N / 16 + 3) / 4;
    const int gn4 = (N + 3) / 4;
    k_gemm_mfma<128, 256, true, 4><<<gw, 256, 0, stream>>>(x, W1p, h1h,
                                                           a_src1, a_dst1, als1, ald1, N);
    k_edge1<<<gn4, 256, 0, stream>>>(h1h, als1, ald1, rowptr, csr, b1, x2h, N);

    // Layer 2: MFMA GEMM [N,256]@[256,64] -> fp16 h2 + fused als2/ald2
    k_gemm_mfma<256, 64, false, 1><<<gw, 256, 0, stream>>>(x2h, W2p, h2h,
                                                           a_src2, a_dst2, als2, ald2, N);
    k_edge2<<<gn4, 256, 0, stream>>>(h2h, als2, ald2, rowptr, csr, b2, out2, N);

    // Pool + FC
    k_pool<<<out_size, 1024, 0, stream>>>(out2, batch, fcW, fcb, out, N);
}